// Round 1
// baseline (208.318 us; speedup 1.0000x reference)
//
#include <hip/hip_runtime.h>

typedef unsigned short u16;
typedef float f32x4 __attribute__((ext_vector_type(4)));
typedef __bf16 bf16x8 __attribute__((ext_vector_type(8)));
typedef unsigned short u16x8 __attribute__((ext_vector_type(8)));

#define DEV static __device__ __forceinline__

DEV u16 f2bf(float f) {
  unsigned int u = __float_as_uint(f);
  u += 0x7FFFu + ((u >> 16) & 1u);   // round-to-nearest-even
  return (u16)(u >> 16);
}
DEV float bf2f(u16 h) { return __uint_as_float(((unsigned int)h) << 16); }
DEV u16 to_bf(float f) { return f2bf(f); }
DEV u16 to_bf(u16 h) { return h; }

// async global->LDS, 16B per lane. LDS dest = wave-uniform base + lane*16.
DEV void gload_lds16(const void* g, void* l) {
  __builtin_amdgcn_global_load_lds(
      (__attribute__((address_space(1))) void*)(unsigned long long)g,
      (__attribute__((address_space(3))) void*)l, 16, 0, 0);
}

// ---------------------------------------------------------------------------
// K0b: convert w_qkv fp32 -> bf16
__global__ __launch_bounds__(256) void convert_w_kernel(
    const float* __restrict__ in, u16* __restrict__ out, int n) {
  int i = blockIdx.x * 256 + threadIdx.x;
  if (i < n) out[i] = f2bf(in[i]);
}

// ---------------------------------------------------------------------------
// Transpose [R=192][C=16384] -> bf16 [C][192], per batch.  64x64 LDS tiles.
template <typename TIN>
__global__ __launch_bounds__(256) void transpose_kernel(
    const TIN* __restrict__ in, u16* __restrict__ out,
    size_t inBatch, size_t outBatch, int C) {
  __shared__ u16 ls[64][66];  // 66: bank-conflict-free column reads
  const int b = blockIdx.z;
  const int c0 = blockIdx.x * 64, r0 = blockIdx.y * 64;
  const TIN* ip = in + (size_t)b * inBatch;
  u16* op = out + (size_t)b * outBatch;
  const int lane = threadIdx.x & 63, w = threadIdx.x >> 6;
#pragma unroll
  for (int i = 0; i < 16; ++i) {
    const int r = i * 4 + w;
    ls[r][lane] = to_bf(ip[(size_t)(r0 + r) * C + c0 + lane]);
  }
  __syncthreads();
#pragma unroll
  for (int i = 0; i < 16; ++i) {
    const int c = i * 4 + w;
    op[(size_t)(c0 + c) * 192 + r0 + lane] = ls[lane][c];
  }
}

// ---------------------------------------------------------------------------
// B^T GEMM (m97-style): C[j][m] = sum_k A[m][k]*B[j][k], K=192 fixed.
// A: [batch][M][192] bf16 (k-contig), B: [batch?][N][192] bf16 (k-contig).
// Tile BM=128 x BN=64, BK=32, 4 waves (2m x 2n), wave = 64m x 32n = 4x2 frags.
template <bool OUT_BF16>
__global__ __launch_bounds__(256) void gemm_bt_kernel(
    const u16* __restrict__ A, const u16* __restrict__ B, void* __restrict__ Cv,
    size_t aBatch, size_t bBatch, size_t cBatch, int ldC) {
  __shared__ __align__(16) char smem[64 * 129 * 4];  // 33024 B
  u16* sA = (u16*)smem;           // [128][32] bf16  (8 KB)
  u16* sB = (u16*)(smem + 8192);  // [64][32]  bf16  (4 KB)
  float* sC = (float*)smem;       // [64][129] f32 epilogue (reuses smem)

  const int tid = threadIdx.x, wave = tid >> 6, lane = tid & 63;
  const int j0 = blockIdx.x * 64, m0 = blockIdx.y * 128, b = blockIdx.z;
  const u16* Ab = A + (size_t)b * aBatch + (size_t)m0 * 192;
  const u16* Bb = B + (size_t)b * bBatch + (size_t)j0 * 192;
  const int wm = wave & 1, wn = wave >> 1;
  const int l15 = lane & 15, lg = lane >> 4;

  f32x4 acc[4][2];
#pragma unroll
  for (int mi = 0; mi < 4; ++mi)
#pragma unroll
    for (int nj = 0; nj < 2; ++nj) acc[mi][nj] = (f32x4){0.f, 0.f, 0.f, 0.f};

  for (int ks = 0; ks < 6; ++ks) {
    const int k0b = ks * 64;  // byte offset within a 384-byte row
#pragma unroll
    for (int i = 0; i < 2; ++i) {  // stage A: 8 KB, 2 instr/wave
      const int flat = (i * 4 + wave) * 1024 + lane * 16;
      const int row = flat >> 6, colb = flat & 63;
      gload_lds16((const char*)Ab + (size_t)row * 384 + k0b + colb,
                  (char*)sA + (i * 4 + wave) * 1024);
    }
    {  // stage B: 4 KB, 1 instr/wave
      const int flat = wave * 1024 + lane * 16;
      const int row = flat >> 6, colb = flat & 63;
      gload_lds16((const char*)Bb + (size_t)row * 384 + k0b + colb,
                  (char*)sB + wave * 1024);
    }
    asm volatile("s_waitcnt vmcnt(0)" ::: "memory");
    __syncthreads();

    bf16x8 af[4], bfv[2];
#pragma unroll
    for (int mi = 0; mi < 4; ++mi)
      af[mi] = *(const bf16x8*)(sA + ((wm * 64 + mi * 16 + l15) * 32 + lg * 8));
#pragma unroll
    for (int nj = 0; nj < 2; ++nj)
      bfv[nj] = *(const bf16x8*)(sB + ((wn * 32 + nj * 16 + l15) * 32 + lg * 8));
#pragma unroll
    for (int mi = 0; mi < 4; ++mi)
#pragma unroll
      for (int nj = 0; nj < 2; ++nj)
        acc[mi][nj] = __builtin_amdgcn_mfma_f32_16x16x32_bf16(
            af[mi], bfv[nj], acc[mi][nj], 0, 0, 0);
    __syncthreads();
  }

  // epilogue: restage to sC[j][m] (pad 129 -> conflict-light), coalesced out
#pragma unroll
  for (int mi = 0; mi < 4; ++mi)
#pragma unroll
    for (int nj = 0; nj < 2; ++nj)
#pragma unroll
      for (int r = 0; r < 4; ++r)
        sC[(wn * 32 + nj * 16 + l15) * 129 + (wm * 64 + mi * 16 + lg * 4 + r)] =
            acc[mi][nj][r];
  __syncthreads();
  if (OUT_BF16) {
    u16* Cb = (u16*)Cv + (size_t)b * cBatch;
#pragma unroll
    for (int i = 0; i < 32; ++i) {
      const int flat = i * 256 + tid;
      const int j = flat >> 7, m = flat & 127;
      Cb[(size_t)(j0 + j) * ldC + m0 + m] = f2bf(sC[j * 129 + m]);
    }
  } else {
    float* Cb = (float*)Cv + (size_t)b * cBatch;
#pragma unroll
    for (int i = 0; i < 32; ++i) {
      const int flat = i * 256 + tid;
      const int j = flat >> 7, m = flat & 127;
      Cb[(size_t)(j0 + j) * ldC + m0 + m] = sC[j * 129 + m];
    }
  }
}

// ---------------------------------------------------------------------------
// Depthwise 3x3 (pad 1), in-place on bf16 [b][576][128][128]; per-channel
// sum-of-squares for the q/k L2 norms. One block per (b, channel).
__global__ __launch_bounds__(256) void dwconv_kernel(
    u16* __restrict__ qkv, const float* __restrict__ wdw,
    float* __restrict__ sq) {
  __shared__ u16 img[16384];  // full 128x128 channel, 32 KB
  __shared__ float red[4];
  const int o = blockIdx.x, b = blockIdx.y;
  const size_t base = ((size_t)b * 576 + o) * 16384;
  const int tid = threadIdx.x, wave = tid >> 6, lane = tid & 63;
#pragma unroll
  for (int i = 0; i < 8; ++i) {
    const int off = (i * 4 + wave) * 1024;
    gload_lds16((const char*)qkv + base * 2 + off + lane * 16, (char*)img + off);
  }
  asm volatile("s_waitcnt vmcnt(0)" ::: "memory");
  __syncthreads();
  float w[9];
#pragma unroll
  for (int j = 0; j < 9; ++j) w[j] = wdw[o * 9 + j];
  float sqacc = 0.f;
  for (int it = 0; it < 8; ++it) {
    const int chunk = it * 256 + tid;  // 2048 chunks of 8 px
    const int px0 = chunk * 8;
    const int y = px0 >> 7, x0 = px0 & 127;
    float acc[8];
#pragma unroll
    for (int j = 0; j < 8; ++j) acc[j] = 0.f;
#pragma unroll
    for (int dy = -1; dy <= 1; ++dy) {
      const int yy = y + dy;
      float v[10];
      if (yy >= 0 && yy <= 127) {
        const u16* rowp = img + yy * 128 + x0;
        u16x8 m = *(const u16x8*)rowp;
#pragma unroll
        for (int j = 0; j < 8; ++j) v[j + 1] = bf2f(m[j]);
        v[0] = (x0 > 0) ? bf2f(rowp[-1]) : 0.f;
        v[9] = (x0 < 120) ? bf2f(rowp[8]) : 0.f;
      } else {
#pragma unroll
        for (int j = 0; j < 10; ++j) v[j] = 0.f;
      }
      const float w0 = w[(dy + 1) * 3], w1 = w[(dy + 1) * 3 + 1],
                  w2 = w[(dy + 1) * 3 + 2];
#pragma unroll
      for (int j = 0; j < 8; ++j) acc[j] += w0 * v[j] + w1 * v[j + 1] + w2 * v[j + 2];
    }
    u16x8 ov;
#pragma unroll
    for (int j = 0; j < 8; ++j) {
      sqacc += acc[j] * acc[j];
      ov[j] = f2bf(acc[j]);
    }
    *(u16x8*)(qkv + base + px0) = ov;  // in-place: all reads came from LDS
  }
#pragma unroll
  for (int s = 32; s > 0; s >>= 1) sqacc += __shfl_xor(sqacc, s, 64);
  if (lane == 0) red[wave] = sqacc;
  __syncthreads();
  if (tid == 0) sq[b * 576 + o] = red[0] + red[1] + red[2] + red[3];
}

// ---------------------------------------------------------------------------
// Gram: partial G[c][d] = sum_n q[c][n]*k[d][n] over a 256-n chunk per wave.
// 48x48 = 3x3 MFMA frags; both operands are k(=n)-contiguous -> same frag path.
__global__ __launch_bounds__(256) void gram_kernel(
    const u16* __restrict__ qkv, float* __restrict__ partial) {
  __shared__ u16 tiles[4 * 3072];  // per-wave [96][32] bf16 (q rows 0-47, k 48-95)
  const int bh = blockIdx.y, b = bh >> 2, h = bh & 3;
  const int wave = threadIdx.x >> 6, lane = threadIdx.x & 63;
  const int chunk = blockIdx.x * 4 + wave;  // 0..63
  const int n0 = chunk * 256;
  const u16* qb = qkv + ((size_t)b * 576 + h * 48) * 16384;
  const u16* kb = qb + (size_t)192 * 16384;
  u16* tl = tiles + wave * 3072;
  f32x4 acc[3][3];
#pragma unroll
  for (int i = 0; i < 3; ++i)
#pragma unroll
    for (int j = 0; j < 3; ++j) acc[i][j] = (f32x4){0.f, 0.f, 0.f, 0.f};

  for (int ks = 0; ks < 8; ++ks) {
    const int nn = n0 + ks * 32;
#pragma unroll
    for (int i = 0; i < 6; ++i) {
      const int flat = i * 1024 + lane * 16;
      const int row = flat >> 6, colb = flat & 63;
      const u16* src = (row < 48) ? (qb + (size_t)row * 16384 + nn)
                                  : (kb + (size_t)(row - 48) * 16384 + nn);
      gload_lds16((const char*)src + colb, (char*)tl + i * 1024);
    }
    asm volatile("s_waitcnt vmcnt(0)" ::: "memory");
    const int l15 = lane & 15, lg = lane >> 4;
    bf16x8 qf[3], kf[3];
#pragma unroll
    for (int f = 0; f < 3; ++f) {
      qf[f] = *(const bf16x8*)(tl + (f * 16 + l15) * 32 + lg * 8);
      kf[f] = *(const bf16x8*)(tl + (48 + f * 16 + l15) * 32 + lg * 8);
    }
#pragma unroll
    for (int i = 0; i < 3; ++i)
#pragma unroll
      for (int j = 0; j < 3; ++j)
        acc[i][j] = __builtin_amdgcn_mfma_f32_16x16x32_bf16(qf[i], kf[j],
                                                            acc[i][j], 0, 0, 0);
    __syncthreads();
  }
  float* pp = partial + ((size_t)bh * 64 + chunk) * 2304;
  const int l15 = lane & 15, lg = lane >> 4;
#pragma unroll
  for (int i = 0; i < 3; ++i)
#pragma unroll
    for (int j = 0; j < 3; ++j)
#pragma unroll
      for (int r = 0; r < 4; ++r)
        pp[(i * 16 + lg * 4 + r) * 48 + (j * 16 + l15)] = acc[i][j][r];
}

// ---------------------------------------------------------------------------
// Reduce partials, normalize by L2 norms * temperature, row softmax.
__global__ __launch_bounds__(256) void softmax_kernel(
    const float* __restrict__ partial, const float* __restrict__ sq,
    const float* __restrict__ temp, float* __restrict__ attn) {
  __shared__ float G[2304];
  __shared__ float nq[48], nk[48];
  const int bh = blockIdx.x, b = bh >> 2, h = bh & 3;
  const int tid = threadIdx.x;
  for (int j = tid; j < 2304; j += 256) {
    float s = 0.f;
    const float* pp = partial + (size_t)bh * 64 * 2304 + j;
#pragma unroll 4
    for (int c = 0; c < 64; ++c) s += pp[(size_t)c * 2304];
    G[j] = s;
  }
  if (tid < 48) {
    nq[tid] = fmaxf(sqrtf(sq[b * 576 + h * 48 + tid]), 1e-12f);
    nk[tid] = fmaxf(sqrtf(sq[b * 576 + 192 + h * 48 + tid]), 1e-12f);
  }
  __syncthreads();
  if (tid < 48) {
    const float tmp = temp[h];
    const int r = tid;
    float L[48];
    float mx = -3.4e38f;
    for (int d = 0; d < 48; ++d) {
      const float v = G[r * 48 + d] / (nq[r] * nk[d]) * tmp;
      L[d] = v;
      mx = fmaxf(mx, v);
    }
    float s = 0.f;
    for (int d = 0; d < 48; ++d) {
      const float e = expf(L[d] - mx);
      L[d] = e;
      s += e;
    }
    const float inv = 1.f / s;
    for (int d = 0; d < 48; ++d)
      attn[(size_t)bh * 2304 + r * 48 + d] = L[d] * inv;
  }
}

// ---------------------------------------------------------------------------
// W_eff[b][o][h*48+d] = sum_c w_proj[o][h*48+c] * attn[b][h][c][d]  (bf16 out)
__global__ __launch_bounds__(256) void weff_kernel(
    const float* __restrict__ attn, const float* __restrict__ wproj,
    u16* __restrict__ weff) {
  __shared__ float at[2304];
  const int oc = blockIdx.x, h = blockIdx.y, b = blockIdx.z;
  const int bh = b * 4 + h;
  for (int j = threadIdx.x; j < 2304; j += 256)
    at[j] = attn[(size_t)bh * 2304 + j];
  __syncthreads();
  for (int j = threadIdx.x; j < 2304; j += 256) {
    const int ol = j / 48, d = j - ol * 48;
    const int o = oc * 48 + ol;
    float s = 0.f;
#pragma unroll 4
    for (int c = 0; c < 48; ++c) s += wproj[o * 192 + h * 48 + c] * at[c * 48 + d];
    weff[((size_t)b * 192 + o) * 192 + h * 48 + d] = f2bf(s);
  }
}

// ---------------------------------------------------------------------------
extern "C" void kernel_launch(void* const* d_in, const int* in_sizes, int n_in,
                              void* d_out, int out_size, void* d_ws,
                              size_t ws_size, hipStream_t stream) {
  (void)in_sizes; (void)n_in; (void)out_size; (void)ws_size;
  const float* x      = (const float*)d_in[0];  // [4][192][128][128]
  const float* w_qkv  = (const float*)d_in[1];  // [576][192]
  const float* w_dw   = (const float*)d_in[2];  // [576][9]
  const float* w_proj = (const float*)d_in[3];  // [192][192]
  const float* temp   = (const float*)d_in[4];  // [4]

  char* ws = (char*)d_ws;
  u16*   qkv     = (u16*)ws;                    // 75,497,472 B
  u16*   vT      = (u16*)(ws + 75497472);       // 25,165,824 B
  float* partial = (float*)(ws + 100663296);    //  9,437,184 B
  float* attn    = (float*)(ws + 110100480);    //    147,456 B
  float* sq      = (float*)(ws + 110247936);    //      9,216 B
  u16*   Wq      = (u16*)(ws + 110257152);      //    221,184 B
  u16*   Weff    = (u16*)(ws + 110478336);      //    294,912 B  (end 110,773,248)
  u16*   Xt      = (u16*)d_out;                 // 25.2 MB scratch, dead before final GEMM

  // w_qkv -> bf16
  convert_w_kernel<<<dim3(432), 256, 0, stream>>>(w_qkv, Wq, 110592);
  // x [b][192][16384] -> Xt [b][16384][192] bf16
  transpose_kernel<float><<<dim3(256, 3, 4), 256, 0, stream>>>(
      x, Xt, (size_t)192 * 16384, (size_t)16384 * 192, 16384);
  // qkv[b][o][n] = sum_c Xt[n][c]*Wq[o][c]   (M=16384, N=576, K=192)
  gemm_bt_kernel<true><<<dim3(9, 128, 4), 256, 0, stream>>>(
      Xt, Wq, qkv, (size_t)16384 * 192, 0, (size_t)576 * 16384, 16384);
  // depthwise 3x3 in-place + per-channel sum-of-squares
  dwconv_kernel<<<dim3(576, 4), 256, 0, stream>>>(qkv, w_dw, sq);
  // gram partials over 64 n-chunks per (b,h)
  gram_kernel<<<dim3(16, 16), 256, 0, stream>>>(qkv, partial);
  // reduce + normalize + softmax
  softmax_kernel<<<dim3(16), 256, 0, stream>>>(partial, sq, temp, attn);
  // fold attn into projection
  weff_kernel<<<dim3(4, 4, 4), 256, 0, stream>>>(attn, w_proj, Weff);
  // v section [b][192][16384] -> vT [b][16384][192]
  transpose_kernel<u16><<<dim3(256, 3, 4), 256, 0, stream>>>(
      qkv + (size_t)384 * 16384, vT, (size_t)576 * 16384, (size_t)16384 * 192,
      16384);
  // out[b][o][n] = sum_c2 vT[n][c2]*Weff[o][c2]  (M=16384, N=192, K=192)
  gemm_bt_kernel<false><<<dim3(3, 128, 4), 256, 0, stream>>>(
      vT, Weff, d_out, (size_t)16384 * 192, (size_t)192 * 192,
      (size_t)192 * 16384, 16384);
}

// Round 2
// 160.374 us; speedup vs baseline: 1.2990x; 1.2990x over previous
//
#include <hip/hip_runtime.h>

typedef unsigned short u16;
typedef float f32x4 __attribute__((ext_vector_type(4)));
typedef __bf16 bf16x8 __attribute__((ext_vector_type(8)));
typedef unsigned short u16x8 __attribute__((ext_vector_type(8)));

#define DEV static __device__ __forceinline__

DEV u16 f2bf(float f) {
  unsigned int u = __float_as_uint(f);
  u += 0x7FFFu + ((u >> 16) & 1u);   // round-to-nearest-even
  return (u16)(u >> 16);
}
DEV float bf2f(u16 h) { return __uint_as_float(((unsigned int)h) << 16); }
DEV u16 to_bf(float f) { return f2bf(f); }
DEV u16 to_bf(u16 h) { return h; }

// async global->LDS, 16B per lane. LDS dest = wave-uniform base + lane*16.
DEV void gload_lds16(const void* g, void* l) {
  __builtin_amdgcn_global_load_lds(
      (__attribute__((address_space(1))) void*)(unsigned long long)g,
      (__attribute__((address_space(3))) void*)l, 16, 0, 0);
}

// ---------------------------------------------------------------------------
// K0b: convert w_qkv fp32 -> bf16
__global__ __launch_bounds__(256) void convert_w_kernel(
    const float* __restrict__ in, u16* __restrict__ out, int n) {
  int i = blockIdx.x * 256 + threadIdx.x;
  if (i < n) out[i] = f2bf(in[i]);
}

// ---------------------------------------------------------------------------
// Transpose [R=192][C=16384] -> bf16 [C][192], per batch.  64x64 LDS tiles.
template <typename TIN>
__global__ __launch_bounds__(256) void transpose_kernel(
    const TIN* __restrict__ in, u16* __restrict__ out,
    size_t inBatch, size_t outBatch, int C) {
  __shared__ u16 ls[64][66];  // 66: bank-conflict-free column reads
  const int b = blockIdx.z;
  const int c0 = blockIdx.x * 64, r0 = blockIdx.y * 64;
  const TIN* ip = in + (size_t)b * inBatch;
  u16* op = out + (size_t)b * outBatch;
  const int lane = threadIdx.x & 63, w = threadIdx.x >> 6;
#pragma unroll
  for (int i = 0; i < 16; ++i) {
    const int r = i * 4 + w;
    ls[r][lane] = to_bf(ip[(size_t)(r0 + r) * C + c0 + lane]);
  }
  __syncthreads();
#pragma unroll
  for (int i = 0; i < 16; ++i) {
    const int c = i * 4 + w;
    op[(size_t)(c0 + c) * 192 + r0 + lane] = ls[lane][c];
  }
}

// ---------------------------------------------------------------------------
// B^T GEMM (m97-style): C[j][m] = sum_k A[m][k]*B[j][k], K=192 fixed.
// A: [batch][M][192] bf16 (k-contig), B: [batch?][N][192] bf16 (k-contig).
// Tile BM=128 x BN=64, BK=32, 4 waves (2m x 2n), wave = 64m x 32n = 4x2 frags.
template <bool OUT_BF16>
__global__ __launch_bounds__(256) void gemm_bt_kernel(
    const u16* __restrict__ A, const u16* __restrict__ B, void* __restrict__ Cv,
    size_t aBatch, size_t bBatch, size_t cBatch, int ldC) {
  __shared__ __align__(16) char smem[64 * 129 * 4];  // 33024 B
  u16* sA = (u16*)smem;           // [128][32] bf16  (8 KB)
  u16* sB = (u16*)(smem + 8192);  // [64][32]  bf16  (4 KB)
  float* sC = (float*)smem;       // [64][129] f32 epilogue (reuses smem)

  const int tid = threadIdx.x, wave = tid >> 6, lane = tid & 63;
  const int j0 = blockIdx.x * 64, m0 = blockIdx.y * 128, b = blockIdx.z;
  const u16* Ab = A + (size_t)b * aBatch + (size_t)m0 * 192;
  const u16* Bb = B + (size_t)b * bBatch + (size_t)j0 * 192;
  const int wm = wave & 1, wn = wave >> 1;
  const int l15 = lane & 15, lg = lane >> 4;

  f32x4 acc[4][2];
#pragma unroll
  for (int mi = 0; mi < 4; ++mi)
#pragma unroll
    for (int nj = 0; nj < 2; ++nj) acc[mi][nj] = (f32x4){0.f, 0.f, 0.f, 0.f};

  for (int ks = 0; ks < 6; ++ks) {
    const int k0b = ks * 64;  // byte offset within a 384-byte row
#pragma unroll
    for (int i = 0; i < 2; ++i) {  // stage A: 8 KB, 2 instr/wave
      const int flat = (i * 4 + wave) * 1024 + lane * 16;
      const int row = flat >> 6, colb = flat & 63;
      gload_lds16((const char*)Ab + (size_t)row * 384 + k0b + colb,
                  (char*)sA + (i * 4 + wave) * 1024);
    }
    {  // stage B: 4 KB, 1 instr/wave
      const int flat = wave * 1024 + lane * 16;
      const int row = flat >> 6, colb = flat & 63;
      gload_lds16((const char*)Bb + (size_t)row * 384 + k0b + colb,
                  (char*)sB + wave * 1024);
    }
    asm volatile("s_waitcnt vmcnt(0)" ::: "memory");
    __syncthreads();

    bf16x8 af[4], bfv[2];
#pragma unroll
    for (int mi = 0; mi < 4; ++mi)
      af[mi] = *(const bf16x8*)(sA + ((wm * 64 + mi * 16 + l15) * 32 + lg * 8));
#pragma unroll
    for (int nj = 0; nj < 2; ++nj)
      bfv[nj] = *(const bf16x8*)(sB + ((wn * 32 + nj * 16 + l15) * 32 + lg * 8));
#pragma unroll
    for (int mi = 0; mi < 4; ++mi)
#pragma unroll
      for (int nj = 0; nj < 2; ++nj)
        acc[mi][nj] = __builtin_amdgcn_mfma_f32_16x16x32_bf16(
            af[mi], bfv[nj], acc[mi][nj], 0, 0, 0);
    __syncthreads();
  }

  // epilogue: restage to sC[j][m] (pad 129 -> conflict-light), coalesced out
#pragma unroll
  for (int mi = 0; mi < 4; ++mi)
#pragma unroll
    for (int nj = 0; nj < 2; ++nj)
#pragma unroll
      for (int r = 0; r < 4; ++r)
        sC[(wn * 32 + nj * 16 + l15) * 129 + (wm * 64 + mi * 16 + lg * 4 + r)] =
            acc[mi][nj][r];
  __syncthreads();
  if (OUT_BF16) {
    u16* Cb = (u16*)Cv + (size_t)b * cBatch;
#pragma unroll
    for (int i = 0; i < 32; ++i) {
      const int flat = i * 256 + tid;
      const int j = flat >> 7, m = flat & 127;
      Cb[(size_t)(j0 + j) * ldC + m0 + m] = f2bf(sC[j * 129 + m]);
    }
  } else {
    float* Cb = (float*)Cv + (size_t)b * cBatch;
#pragma unroll
    for (int i = 0; i < 32; ++i) {
      const int flat = i * 256 + tid;
      const int j = flat >> 7, m = flat & 127;
      Cb[(size_t)(j0 + j) * ldC + m0 + m] = sC[j * 129 + m];
    }
  }
}

// ---------------------------------------------------------------------------
// Depthwise 3x3 (pad 1), in-place on bf16 [b][576][128][128]; per-channel
// sum-of-squares for the q/k L2 norms. One block per (b, channel).
__global__ __launch_bounds__(256) void dwconv_kernel(
    u16* __restrict__ qkv, const float* __restrict__ wdw,
    float* __restrict__ sq) {
  __shared__ u16 img[16384];  // full 128x128 channel, 32 KB
  __shared__ float red[4];
  const int o = blockIdx.x, b = blockIdx.y;
  const size_t base = ((size_t)b * 576 + o) * 16384;
  const int tid = threadIdx.x, wave = tid >> 6, lane = tid & 63;
#pragma unroll
  for (int i = 0; i < 8; ++i) {
    const int off = (i * 4 + wave) * 1024;
    gload_lds16((const char*)qkv + base * 2 + off + lane * 16, (char*)img + off);
  }
  asm volatile("s_waitcnt vmcnt(0)" ::: "memory");
  __syncthreads();
  float w[9];
#pragma unroll
  for (int j = 0; j < 9; ++j) w[j] = wdw[o * 9 + j];
  float sqacc = 0.f;
  for (int it = 0; it < 8; ++it) {
    const int chunk = it * 256 + tid;  // 2048 chunks of 8 px
    const int px0 = chunk * 8;
    const int y = px0 >> 7, x0 = px0 & 127;
    float acc[8];
#pragma unroll
    for (int j = 0; j < 8; ++j) acc[j] = 0.f;
#pragma unroll
    for (int dy = -1; dy <= 1; ++dy) {
      const int yy = y + dy;
      float v[10];
      if (yy >= 0 && yy <= 127) {
        const u16* rowp = img + yy * 128 + x0;
        u16x8 m = *(const u16x8*)rowp;
#pragma unroll
        for (int j = 0; j < 8; ++j) v[j + 1] = bf2f(m[j]);
        v[0] = (x0 > 0) ? bf2f(rowp[-1]) : 0.f;
        v[9] = (x0 < 120) ? bf2f(rowp[8]) : 0.f;
      } else {
#pragma unroll
        for (int j = 0; j < 10; ++j) v[j] = 0.f;
      }
      const float w0 = w[(dy + 1) * 3], w1 = w[(dy + 1) * 3 + 1],
                  w2 = w[(dy + 1) * 3 + 2];
#pragma unroll
      for (int j = 0; j < 8; ++j) acc[j] += w0 * v[j] + w1 * v[j + 1] + w2 * v[j + 2];
    }
    u16x8 ov;
#pragma unroll
    for (int j = 0; j < 8; ++j) {
      sqacc += acc[j] * acc[j];
      ov[j] = f2bf(acc[j]);
    }
    *(u16x8*)(qkv + base + px0) = ov;  // in-place: all reads came from LDS
  }
#pragma unroll
  for (int s = 32; s > 0; s >>= 1) sqacc += __shfl_xor(sqacc, s, 64);
  if (lane == 0) red[wave] = sqacc;
  __syncthreads();
  if (tid == 0) sq[b * 576 + o] = red[0] + red[1] + red[2] + red[3];
}

// ---------------------------------------------------------------------------
// Gram: G_partial[c][d] = sum_n q[c][n]*k[d][n] over a 1024-n block (4 waves x
// 256 n each, reduced in-block through LDS). Partial layout TRANSPOSED:
// partial[bh][pos][chunk16] so stage-2 reads are contiguous f32x4.
// No per-K-step barrier: each wave's LDS tile is private.
__global__ __launch_bounds__(256) void gram_kernel(
    const u16* __restrict__ qkv, float* __restrict__ partial) {
  __shared__ u16 tiles[4 * 3072];   // per-wave [96][32] bf16 (q 0-47, k 48-95)
  __shared__ float red[4 * 2304];   // per-wave gram copies for in-block reduce
  const int bh = blockIdx.y, b = bh >> 2, h = bh & 3;
  const int g = blockIdx.x;                  // chunk-group 0..15
  const int wave = threadIdx.x >> 6, lane = threadIdx.x & 63;
  const int n0 = g * 1024 + wave * 256;
  const u16* qb = qkv + ((size_t)b * 576 + h * 48) * 16384;
  const u16* kb = qb + (size_t)192 * 16384;
  u16* tl = tiles + wave * 3072;
  f32x4 acc[3][3];
#pragma unroll
  for (int i = 0; i < 3; ++i)
#pragma unroll
    for (int j = 0; j < 3; ++j) acc[i][j] = (f32x4){0.f, 0.f, 0.f, 0.f};

  for (int ks = 0; ks < 8; ++ks) {
    const int nn = n0 + ks * 32;
    // ds_reads of the previous iteration must have completed before the
    // async loads may overwrite this wave's tile
    asm volatile("s_waitcnt lgkmcnt(0)" ::: "memory");
#pragma unroll
    for (int i = 0; i < 6; ++i) {
      const int flat = i * 1024 + lane * 16;
      const int row = flat >> 6, colb = flat & 63;
      const u16* src = (row < 48) ? (qb + (size_t)row * 16384 + nn)
                                  : (kb + (size_t)(row - 48) * 16384 + nn);
      gload_lds16((const char*)src + colb, (char*)tl + i * 1024);
    }
    asm volatile("s_waitcnt vmcnt(0)" ::: "memory");
    const int l15 = lane & 15, lg = lane >> 4;
    bf16x8 qf[3], kf[3];
#pragma unroll
    for (int f = 0; f < 3; ++f) {
      qf[f] = *(const bf16x8*)(tl + (f * 16 + l15) * 32 + lg * 8);
      kf[f] = *(const bf16x8*)(tl + (48 + f * 16 + l15) * 32 + lg * 8);
    }
#pragma unroll
    for (int i = 0; i < 3; ++i)
#pragma unroll
      for (int j = 0; j < 3; ++j)
        acc[i][j] = __builtin_amdgcn_mfma_f32_16x16x32_bf16(qf[i], kf[j],
                                                            acc[i][j], 0, 0, 0);
  }
  // in-block reduce over the 4 waves
  {
    const int l15 = lane & 15, lg = lane >> 4;
    float* rw = red + wave * 2304;
#pragma unroll
    for (int i = 0; i < 3; ++i)
#pragma unroll
      for (int j = 0; j < 3; ++j)
#pragma unroll
        for (int r = 0; r < 4; ++r)
          rw[(i * 16 + lg * 4 + r) * 48 + (j * 16 + l15)] = acc[i][j][r];
  }
  __syncthreads();
#pragma unroll
  for (int it = 0; it < 9; ++it) {
    const int p = it * 256 + threadIdx.x;
    const float s = red[p] + red[2304 + p] + red[4608 + p] + red[6912 + p];
    partial[((size_t)bh * 2304 + p) * 16 + g] = s;
  }
}

// ---------------------------------------------------------------------------
// Stage 2: reduce 16 chunks (contiguous f32x4 loads), L2-normalize with
// precomputed norms * temperature, row softmax, then fold attn into the
// projection: Weff[b][o][h*48+d] = sum_c wproj[o][h*48+c] * attn[c][d].
__global__ __launch_bounds__(256) void softmax_weff_kernel(
    const float* __restrict__ partial, const float* __restrict__ sq,
    const float* __restrict__ temp, const float* __restrict__ wproj,
    u16* __restrict__ weff) {
  __shared__ float G[2304];        // gram -> attn (in place)
  __shared__ float wp[192 * 49];   // wproj slice, pad 49 (odd bank stride)
  __shared__ float nq[48], nk[48];
  const int bh = blockIdx.x, b = bh >> 2, h = bh & 3;
  const int tid = threadIdx.x;
#pragma unroll
  for (int it = 0; it < 36; ++it) {  // load wproj [192][h*48 .. h*48+48)
    const int j = it * 256 + tid;
    const int o = j / 48, c = j - o * 48;
    wp[o * 49 + c] = wproj[o * 192 + h * 48 + c];
  }
#pragma unroll
  for (int it = 0; it < 9; ++it) {   // reduce 16 partial chunks, coalesced
    const int p = it * 256 + tid;
    const f32x4* pp = (const f32x4*)(partial + ((size_t)bh * 2304 + p) * 16);
    const f32x4 a = pp[0] + pp[1] + pp[2] + pp[3];
    G[p] = a.x + a.y + a.z + a.w;
  }
  if (tid < 48) {
    nq[tid] = fmaxf(sqrtf(sq[b * 576 + h * 48 + tid]), 1e-12f);
    nk[tid] = fmaxf(sqrtf(sq[b * 576 + 192 + h * 48 + tid]), 1e-12f);
  }
  __syncthreads();
  if (tid < 48) {  // row softmax (48 rows)
    const int r = tid;
    const float inq = temp[h] / nq[r];
    float L[48];
    float mx = -3.4e38f;
#pragma unroll 4
    for (int d = 0; d < 48; ++d) {
      const float v = G[r * 48 + d] * inq / nk[d];
      L[d] = v;
      mx = fmaxf(mx, v);
    }
    float s = 0.f;
#pragma unroll 4
    for (int d = 0; d < 48; ++d) {
      const float e = __expf(L[d] - mx);
      L[d] = e;
      s += e;
    }
    const float inv = 1.f / s;
#pragma unroll 4
    for (int d = 0; d < 48; ++d) G[r * 48 + d] = L[d] * inv;
  }
  __syncthreads();
  if (tid < 192) {  // Weff row o = tid: 12 f32x4 accumulators over 48 c
    const int o = tid;
    f32x4 acc[12];
#pragma unroll
    for (int dv = 0; dv < 12; ++dv) acc[dv] = (f32x4){0.f, 0.f, 0.f, 0.f};
    for (int c = 0; c < 48; ++c) {
      const float w = wp[o * 49 + c];
      const f32x4* at = (const f32x4*)(G + c * 48);  // broadcast reads
#pragma unroll
      for (int dv = 0; dv < 12; ++dv) acc[dv] += w * at[dv];
    }
    u16* op = weff + ((size_t)b * 192 + o) * 192 + h * 48;
#pragma unroll
    for (int g8 = 0; g8 < 6; ++g8) {
      u16x8 ov;
#pragma unroll
      for (int j = 0; j < 8; ++j) {
        const int d = g8 * 8 + j;
        ov[j] = f2bf(acc[d >> 2][d & 3]);
      }
      *(u16x8*)(op + g8 * 8) = ov;
    }
  }
}

// ---------------------------------------------------------------------------
extern "C" void kernel_launch(void* const* d_in, const int* in_sizes, int n_in,
                              void* d_out, int out_size, void* d_ws,
                              size_t ws_size, hipStream_t stream) {
  (void)in_sizes; (void)n_in; (void)out_size; (void)ws_size;
  const float* x      = (const float*)d_in[0];  // [4][192][128][128]
  const float* w_qkv  = (const float*)d_in[1];  // [576][192]
  const float* w_dw   = (const float*)d_in[2];  // [576][9]
  const float* w_proj = (const float*)d_in[3];  // [192][192]
  const float* temp   = (const float*)d_in[4];  // [4]

  char* ws = (char*)d_ws;
  u16*   qkv     = (u16*)ws;                    // 75,497,472 B
  u16*   vT      = (u16*)(ws + 75497472);       // 25,165,824 B
  float* partial = (float*)(ws + 100663296);    //  2,359,296 B  [16][2304][16]
  float* sq      = (float*)(ws + 103022592);    //      9,216 B
  u16*   Wq      = (u16*)(ws + 103031808);      //    221,184 B
  u16*   Weff    = (u16*)(ws + 103252992);      //    294,912 B
  u16*   Xt      = (u16*)d_out;                 // 25.2 MB scratch, dead before final GEMM

  // w_qkv -> bf16
  convert_w_kernel<<<dim3(432), 256, 0, stream>>>(w_qkv, Wq, 110592);
  // x [b][192][16384] -> Xt [b][16384][192] bf16
  transpose_kernel<float><<<dim3(256, 3, 4), 256, 0, stream>>>(
      x, Xt, (size_t)192 * 16384, (size_t)16384 * 192, 16384);
  // qkv[b][o][n] = sum_c Xt[n][c]*Wq[o][c]   (M=16384, N=576, K=192)
  gemm_bt_kernel<true><<<dim3(9, 128, 4), 256, 0, stream>>>(
      Xt, Wq, qkv, (size_t)16384 * 192, 0, (size_t)576 * 16384, 16384);
  // depthwise 3x3 in-place + per-channel sum-of-squares
  dwconv_kernel<<<dim3(576, 4), 256, 0, stream>>>(qkv, w_dw, sq);
  // gram partials: 16 chunk-groups per (b,h), in-block wave reduction
  gram_kernel<<<dim3(16, 16), 256, 0, stream>>>(qkv, partial);
  // reduce + normalize + softmax + fold into projection
  softmax_weff_kernel<<<dim3(16), 256, 0, stream>>>(partial, sq, temp, w_proj,
                                                    Weff);
  // v section [b][192][16384] -> vT [b][16384][192]
  transpose_kernel<u16><<<dim3(256, 3, 4), 256, 0, stream>>>(
      qkv + (size_t)384 * 16384, vT, (size_t)576 * 16384, (size_t)16384 * 192,
      16384);
  // out[b][o][n] = sum_c2 vT[n][c2]*Weff[o][c2]  (M=16384, K=192)
  gemm_bt_kernel<false><<<dim3(3, 128, 4), 256, 0, stream>>>(
      vT, Weff, d_out, (size_t)16384 * 192, (size_t)192 * 192,
      (size_t)192 * 16384, 16384);
}

// Round 3
// 143.031 us; speedup vs baseline: 1.4565x; 1.1213x over previous
//
#include <hip/hip_runtime.h>

typedef unsigned short u16;
typedef float f32x4 __attribute__((ext_vector_type(4)));
typedef __bf16 bf16x8 __attribute__((ext_vector_type(8)));
typedef unsigned short u16x8 __attribute__((ext_vector_type(8)));

#define DEV static __device__ __forceinline__

DEV u16 f2bf(float f) {
  unsigned int u = __float_as_uint(f);
  u += 0x7FFFu + ((u >> 16) & 1u);   // round-to-nearest-even
  return (u16)(u >> 16);
}
DEV float bf2f(u16 h) { return __uint_as_float(((unsigned int)h) << 16); }

// async global->LDS, 16B per lane. LDS dest = wave-uniform base + lane*16.
DEV void gload_lds16(const void* g, void* l) {
  __builtin_amdgcn_global_load_lds(
      (__attribute__((address_space(1))) void*)(unsigned long long)g,
      (__attribute__((address_space(3))) void*)l, 16, 0, 0);
}

// ---------------------------------------------------------------------------
// K0b: convert w_qkv fp32 -> bf16
__global__ __launch_bounds__(256) void convert_w_kernel(
    const float* __restrict__ in, u16* __restrict__ out, int n) {
  int i = blockIdx.x * 256 + threadIdx.x;
  if (i < n) out[i] = f2bf(in[i]);
}

// ---------------------------------------------------------------------------
// Transpose [R=192][C=16384] fp32 -> bf16 [C][192], per batch. 64x64 tiles.
// Input vectorized f32x4 (16 B/lane, 1 KB per wave instruction).
__global__ __launch_bounds__(256) void transpose_f32_kernel(
    const float* __restrict__ in, u16* __restrict__ out,
    size_t inBatch, size_t outBatch, int C) {
  __shared__ u16 ls[64][66];  // pad 66: column reads 2-way (free)
  const int b = blockIdx.z;
  const int c0 = blockIdx.x * 64, r0 = blockIdx.y * 64;
  const float* ip = in + (size_t)b * inBatch;
  u16* op = out + (size_t)b * outBatch;
  const int t = threadIdx.x;
  const int rr = t >> 4, cg = t & 15;  // 16 rows x 16 col-groups per pass
#pragma unroll
  for (int i = 0; i < 4; ++i) {
    const int r = i * 16 + rr;
    const f32x4 v = *(const f32x4*)(ip + (size_t)(r0 + r) * C + c0 + cg * 4);
    ls[r][cg * 4 + 0] = f2bf(v.x);
    ls[r][cg * 4 + 1] = f2bf(v.y);
    ls[r][cg * 4 + 2] = f2bf(v.z);
    ls[r][cg * 4 + 3] = f2bf(v.w);
  }
  __syncthreads();
  const int lane = t & 63, w = t >> 6;
#pragma unroll
  for (int i = 0; i < 16; ++i) {
    const int c = i * 4 + w;
    op[(size_t)(c0 + c) * 192 + r0 + lane] = ls[lane][c];
  }
}

// bf16 variant (v-path). Input u16x8 (16 B/lane).
__global__ __launch_bounds__(256) void transpose_u16_kernel(
    const u16* __restrict__ in, u16* __restrict__ out,
    size_t inBatch, size_t outBatch, int C) {
  __shared__ u16 ls[64][66];
  const int b = blockIdx.z;
  const int c0 = blockIdx.x * 64, r0 = blockIdx.y * 64;
  const u16* ip = in + (size_t)b * inBatch;
  u16* op = out + (size_t)b * outBatch;
  const int t = threadIdx.x;
  const int rr = t >> 3, cg = t & 7;  // 32 rows x 8 col-groups per pass
#pragma unroll
  for (int i = 0; i < 2; ++i) {
    const int r = i * 32 + rr;
    const u16x8 v = *(const u16x8*)(ip + (size_t)(r0 + r) * C + c0 + cg * 8);
#pragma unroll
    for (int j = 0; j < 8; ++j) ls[r][cg * 8 + j] = v[j];
  }
  __syncthreads();
  const int lane = t & 63, w = t >> 6;
#pragma unroll
  for (int i = 0; i < 16; ++i) {
    const int c = i * 4 + w;
    op[(size_t)(c0 + c) * 192 + r0 + lane] = ls[lane][c];
  }
}

// ---------------------------------------------------------------------------
// B^T GEMM, full-K single-shot staging. C[j][m] = sum_k A[m][k]*B[j][k],
// K=192. Tile BM=128 x BN=64, 4 waves (2m x 2n), wave = 64m x 32n.
// LDS content XOR-swizzled (byte ^ ((row&7)<<4)) via pre-swizzled global
// source (gload_lds writes linearly) -> conflict-free ds_read_b128.
// 1D grid, m-major + bijective XCD chunk swizzle: all j-blocks of an A-panel
// land on one XCD -> A fetched once per XCD L2.
template <bool OUT_BF16, int NJ>
__global__ __launch_bounds__(256, 2) void gemm_bt_kernel(
    const u16* __restrict__ A, const u16* __restrict__ B, void* __restrict__ Cv,
    size_t aBatch, size_t bBatch, size_t cBatch, int ldC, int nwg) {
  __shared__ __align__(16) char smem[73728];
  u16* sA = (u16*)smem;            // [128][192] bf16, swizzled content
  u16* sB = (u16*)(smem + 49152);  // [64][192]
  float* sC = (float*)smem;        // [64][129] f32 epilogue alias

  const int tid = threadIdx.x, wave = tid >> 6, lane = tid & 63;
  // XCD swizzle: phys p -> logical id so each XCD gets a contiguous id chunk
  const int p = blockIdx.x;
  const int id = (p & 7) * (nwg >> 3) + (p >> 3);
  const int j = id % NJ;
  const int tt = id / NJ;
  const int m0 = (tt & 127) * 128, j0 = j * 64, b = tt >> 7;

  const char* Ab = (const char*)(A + (size_t)b * aBatch + (size_t)m0 * 192);
  const char* Bb = (const char*)(B + (size_t)b * bBatch + (size_t)j0 * 192);

  // ---- stage whole K: A 48 KB (12 chunks/wave), B 24 KB (6 chunks/wave)
#pragma unroll
  for (int i = 0; i < 12; ++i) {
    const int c = i * 4 + wave;
    const int d = c * 1024 + lane * 16;
    const int row = d / 384, inrow = d - row * 384;
    gload_lds16(Ab + row * 384 + (inrow ^ ((row & 7) << 4)),
                (char*)sA + c * 1024);
  }
#pragma unroll
  for (int i = 0; i < 6; ++i) {
    const int c = i * 4 + wave;
    const int d = c * 1024 + lane * 16;
    const int row = d / 384, inrow = d - row * 384;
    gload_lds16(Bb + row * 384 + (inrow ^ ((row & 7) << 4)),
                (char*)sB + c * 1024);
  }
  asm volatile("s_waitcnt vmcnt(0)" ::: "memory");
  __syncthreads();

  // ---- compute: 48 MFMA / wave, no further barriers
  const int wm = wave & 1, wn = wave >> 1;
  const int l15 = lane & 15, lg = lane >> 4;
  const int swm = (l15 & 7) << 4;  // row&7 == l15&7 for all fragments
  const int rA0 = (wm * 64 + l15) * 384, rB0 = (wn * 32 + l15) * 384;

  f32x4 acc[4][2];
#pragma unroll
  for (int mi = 0; mi < 4; ++mi)
#pragma unroll
    for (int nj = 0; nj < 2; ++nj) acc[mi][nj] = (f32x4){0.f, 0.f, 0.f, 0.f};

#pragma unroll
  for (int ks = 0; ks < 6; ++ks) {
    const int col = (ks * 64 + lg * 16) ^ swm;
    bf16x8 af[4], bfv[2];
#pragma unroll
    for (int mi = 0; mi < 4; ++mi)
      af[mi] = *(const bf16x8*)((char*)sA + rA0 + mi * 16 * 384 + col);
#pragma unroll
    for (int nj = 0; nj < 2; ++nj)
      bfv[nj] = *(const bf16x8*)((char*)sB + rB0 + nj * 16 * 384 + col);
#pragma unroll
    for (int mi = 0; mi < 4; ++mi)
#pragma unroll
      for (int nj = 0; nj < 2; ++nj)
        acc[mi][nj] = __builtin_amdgcn_mfma_f32_16x16x32_bf16(
            af[mi], bfv[nj], acc[mi][nj], 0, 0, 0);
  }
  __syncthreads();  // all ds_reads done before sC overwrites sA

  // ---- epilogue: restage to sC[j][m], coalesced global write
#pragma unroll
  for (int mi = 0; mi < 4; ++mi)
#pragma unroll
    for (int nj = 0; nj < 2; ++nj)
#pragma unroll
      for (int r = 0; r < 4; ++r)
        sC[(wn * 32 + nj * 16 + l15) * 129 + (wm * 64 + mi * 16 + lg * 4 + r)] =
            acc[mi][nj][r];
  __syncthreads();
  if (OUT_BF16) {
    u16* Cb = (u16*)Cv + (size_t)b * cBatch;
#pragma unroll
    for (int i = 0; i < 32; ++i) {
      const int flat = i * 256 + tid;
      const int jj = flat >> 7, mm = flat & 127;
      Cb[(size_t)(j0 + jj) * ldC + m0 + mm] = f2bf(sC[jj * 129 + mm]);
    }
  } else {
    float* Cb = (float*)Cv + (size_t)b * cBatch;
#pragma unroll
    for (int i = 0; i < 32; ++i) {
      const int flat = i * 256 + tid;
      const int jj = flat >> 7, mm = flat & 127;
      Cb[(size_t)(j0 + jj) * ldC + m0 + mm] = sC[jj * 129 + mm];
    }
  }
}

// ---------------------------------------------------------------------------
// Depthwise 3x3 (pad 1), in-place on bf16 [b][576][128][128]; per-channel
// sum-of-squares for the q/k L2 norms. One block per (b, channel).
__global__ __launch_bounds__(256) void dwconv_kernel(
    u16* __restrict__ qkv, const float* __restrict__ wdw,
    float* __restrict__ sq) {
  __shared__ u16 img[16384];  // full 128x128 channel, 32 KB
  __shared__ float red[4];
  const int o = blockIdx.x, b = blockIdx.y;
  const size_t base = ((size_t)b * 576 + o) * 16384;
  const int tid = threadIdx.x, wave = tid >> 6, lane = tid & 63;
#pragma unroll
  for (int i = 0; i < 8; ++i) {
    const int off = (i * 4 + wave) * 1024;
    gload_lds16((const char*)qkv + base * 2 + off + lane * 16, (char*)img + off);
  }
  asm volatile("s_waitcnt vmcnt(0)" ::: "memory");
  __syncthreads();
  float w[9];
#pragma unroll
  for (int j = 0; j < 9; ++j) w[j] = wdw[o * 9 + j];
  float sqacc = 0.f;
  for (int it = 0; it < 8; ++it) {
    const int chunk = it * 256 + tid;  // 2048 chunks of 8 px
    const int px0 = chunk * 8;
    const int y = px0 >> 7, x0 = px0 & 127;
    float acc[8];
#pragma unroll
    for (int j = 0; j < 8; ++j) acc[j] = 0.f;
#pragma unroll
    for (int dy = -1; dy <= 1; ++dy) {
      const int yy = y + dy;
      float v[10];
      if (yy >= 0 && yy <= 127) {
        const u16* rowp = img + yy * 128 + x0;
        u16x8 m = *(const u16x8*)rowp;
#pragma unroll
        for (int j = 0; j < 8; ++j) v[j + 1] = bf2f(m[j]);
        v[0] = (x0 > 0) ? bf2f(rowp[-1]) : 0.f;
        v[9] = (x0 < 120) ? bf2f(rowp[8]) : 0.f;
      } else {
#pragma unroll
        for (int j = 0; j < 10; ++j) v[j] = 0.f;
      }
      const float w0 = w[(dy + 1) * 3], w1 = w[(dy + 1) * 3 + 1],
                  w2 = w[(dy + 1) * 3 + 2];
#pragma unroll
      for (int j = 0; j < 8; ++j) acc[j] += w0 * v[j] + w1 * v[j + 1] + w2 * v[j + 2];
    }
    u16x8 ov;
#pragma unroll
    for (int j = 0; j < 8; ++j) {
      sqacc += acc[j] * acc[j];
      ov[j] = f2bf(acc[j]);
    }
    *(u16x8*)(qkv + base + px0) = ov;  // in-place: all reads came from LDS
  }
#pragma unroll
  for (int s = 32; s > 0; s >>= 1) sqacc += __shfl_xor(sqacc, s, 64);
  if (lane == 0) red[wave] = sqacc;
  __syncthreads();
  if (tid == 0) sq[b * 576 + o] = red[0] + red[1] + red[2] + red[3];
}

// ---------------------------------------------------------------------------
// Gram: G_partial[c][d] = sum_n q[c][n]*k[d][n] over a 1024-n block (4 waves x
// 256 n each, reduced in-block through LDS). Partial layout transposed:
// partial[bh][pos][chunk16] so stage-2 reads are contiguous f32x4.
__global__ __launch_bounds__(256) void gram_kernel(
    const u16* __restrict__ qkv, float* __restrict__ partial) {
  __shared__ u16 tiles[4 * 3072];   // per-wave [96][32] bf16 (q 0-47, k 48-95)
  __shared__ float red[4 * 2304];   // per-wave gram copies for in-block reduce
  const int bh = blockIdx.y, b = bh >> 2, h = bh & 3;
  const int g = blockIdx.x;                  // chunk-group 0..15
  const int wave = threadIdx.x >> 6, lane = threadIdx.x & 63;
  const int n0 = g * 1024 + wave * 256;
  const u16* qb = qkv + ((size_t)b * 576 + h * 48) * 16384;
  const u16* kb = qb + (size_t)192 * 16384;
  u16* tl = tiles + wave * 3072;
  f32x4 acc[3][3];
#pragma unroll
  for (int i = 0; i < 3; ++i)
#pragma unroll
    for (int j = 0; j < 3; ++j) acc[i][j] = (f32x4){0.f, 0.f, 0.f, 0.f};

  for (int ks = 0; ks < 8; ++ks) {
    const int nn = n0 + ks * 32;
    asm volatile("s_waitcnt lgkmcnt(0)" ::: "memory");
#pragma unroll
    for (int i = 0; i < 6; ++i) {
      const int flat = i * 1024 + lane * 16;
      const int row = flat >> 6, colb = flat & 63;
      const u16* src = (row < 48) ? (qb + (size_t)row * 16384 + nn)
                                  : (kb + (size_t)(row - 48) * 16384 + nn);
      gload_lds16((const char*)src + colb, (char*)tl + i * 1024);
    }
    asm volatile("s_waitcnt vmcnt(0)" ::: "memory");
    const int l15 = lane & 15, lg = lane >> 4;
    bf16x8 qf[3], kf[3];
#pragma unroll
    for (int f = 0; f < 3; ++f) {
      qf[f] = *(const bf16x8*)(tl + (f * 16 + l15) * 32 + lg * 8);
      kf[f] = *(const bf16x8*)(tl + (48 + f * 16 + l15) * 32 + lg * 8);
    }
#pragma unroll
    for (int i = 0; i < 3; ++i)
#pragma unroll
      for (int j = 0; j < 3; ++j)
        acc[i][j] = __builtin_amdgcn_mfma_f32_16x16x32_bf16(qf[i], kf[j],
                                                            acc[i][j], 0, 0, 0);
  }
  // in-block reduce over the 4 waves
  {
    const int l15 = lane & 15, lg = lane >> 4;
    float* rw = red + wave * 2304;
#pragma unroll
    for (int i = 0; i < 3; ++i)
#pragma unroll
      for (int j = 0; j < 3; ++j)
#pragma unroll
        for (int r = 0; r < 4; ++r)
          rw[(i * 16 + lg * 4 + r) * 48 + (j * 16 + l15)] = acc[i][j][r];
  }
  __syncthreads();
#pragma unroll
  for (int it = 0; it < 9; ++it) {
    const int p = it * 256 + threadIdx.x;
    const float s = red[p] + red[2304 + p] + red[4608 + p] + red[6912 + p];
    partial[((size_t)bh * 2304 + p) * 16 + g] = s;
  }
}

// ---------------------------------------------------------------------------
// Stage 2: reduce 16 chunks, normalize, softmax, fold attn into projection.
__global__ __launch_bounds__(256) void softmax_weff_kernel(
    const float* __restrict__ partial, const float* __restrict__ sq,
    const float* __restrict__ temp, const float* __restrict__ wproj,
    u16* __restrict__ weff) {
  __shared__ float G[2304];        // gram -> attn (in place)
  __shared__ float wp[192 * 49];   // wproj slice, pad 49 (odd bank stride)
  __shared__ float nq[48], nk[48];
  const int bh = blockIdx.x, b = bh >> 2, h = bh & 3;
  const int tid = threadIdx.x;
#pragma unroll
  for (int it = 0; it < 36; ++it) {  // load wproj [192][h*48 .. h*48+48)
    const int j = it * 256 + tid;
    const int o = j / 48, c = j - o * 48;
    wp[o * 49 + c] = wproj[o * 192 + h * 48 + c];
  }
#pragma unroll
  for (int it = 0; it < 9; ++it) {   // reduce 16 partial chunks, coalesced
    const int p = it * 256 + tid;
    const f32x4* pp = (const f32x4*)(partial + ((size_t)bh * 2304 + p) * 16);
    const f32x4 a = pp[0] + pp[1] + pp[2] + pp[3];
    G[p] = a.x + a.y + a.z + a.w;
  }
  if (tid < 48) {
    nq[tid] = fmaxf(sqrtf(sq[b * 576 + h * 48 + tid]), 1e-12f);
    nk[tid] = fmaxf(sqrtf(sq[b * 576 + 192 + h * 48 + tid]), 1e-12f);
  }
  __syncthreads();
  if (tid < 48) {  // row softmax (48 rows)
    const int r = tid;
    const float inq = temp[h] / nq[r];
    float L[48];
    float mx = -3.4e38f;
#pragma unroll 4
    for (int d = 0; d < 48; ++d) {
      const float v = G[r * 48 + d] * inq / nk[d];
      L[d] = v;
      mx = fmaxf(mx, v);
    }
    float s = 0.f;
#pragma unroll 4
    for (int d = 0; d < 48; ++d) {
      const float e = __expf(L[d] - mx);
      L[d] = e;
      s += e;
    }
    const float inv = 1.f / s;
#pragma unroll 4
    for (int d = 0; d < 48; ++d) G[r * 48 + d] = L[d] * inv;
  }
  __syncthreads();
  if (tid < 192) {  // Weff row o = tid
    const int o = tid;
    f32x4 acc[12];
#pragma unroll
    for (int dv = 0; dv < 12; ++dv) acc[dv] = (f32x4){0.f, 0.f, 0.f, 0.f};
    for (int c = 0; c < 48; ++c) {
      const float w = wp[o * 49 + c];
      const f32x4* at = (const f32x4*)(G + c * 48);  // broadcast reads
#pragma unroll
      for (int dv = 0; dv < 12; ++dv) acc[dv] += w * at[dv];
    }
    u16* op = weff + ((size_t)b * 192 + o) * 192 + h * 48;
#pragma unroll
    for (int g8 = 0; g8 < 6; ++g8) {
      u16x8 ov;
#pragma unroll
      for (int j = 0; j < 8; ++j) {
        const int d = g8 * 8 + j;
        ov[j] = f2bf(acc[d >> 2][d & 3]);
      }
      *(u16x8*)(op + g8 * 8) = ov;
    }
  }
}

// ---------------------------------------------------------------------------
extern "C" void kernel_launch(void* const* d_in, const int* in_sizes, int n_in,
                              void* d_out, int out_size, void* d_ws,
                              size_t ws_size, hipStream_t stream) {
  (void)in_sizes; (void)n_in; (void)out_size; (void)ws_size;
  const float* x      = (const float*)d_in[0];  // [4][192][128][128]
  const float* w_qkv  = (const float*)d_in[1];  // [576][192]
  const float* w_dw   = (const float*)d_in[2];  // [576][9]
  const float* w_proj = (const float*)d_in[3];  // [192][192]
  const float* temp   = (const float*)d_in[4];  // [4]

  char* ws = (char*)d_ws;
  u16*   qkv     = (u16*)ws;                    // 75,497,472 B
  u16*   vT      = (u16*)(ws + 75497472);       // 25,165,824 B
  float* partial = (float*)(ws + 100663296);    //  2,359,296 B  [16][2304][16]
  float* sq      = (float*)(ws + 103022592);    //      9,216 B
  u16*   Wq      = (u16*)(ws + 103031808);      //    221,184 B
  u16*   Weff    = (u16*)(ws + 103252992);      //    294,912 B
  u16*   Xt      = (u16*)d_out;                 // 25.2 MB scratch, dead before final GEMM

  // w_qkv -> bf16
  convert_w_kernel<<<dim3(432), 256, 0, stream>>>(w_qkv, Wq, 110592);
  // x [b][192][16384] -> Xt [b][16384][192] bf16
  transpose_f32_kernel<<<dim3(256, 3, 4), 256, 0, stream>>>(
      x, Xt, (size_t)192 * 16384, (size_t)16384 * 192, 16384);
  // qkv[b][o][n] = sum_c Xt[n][c]*Wq[o][c]   (M=16384x4, N=576, K=192)
  gemm_bt_kernel<true, 9><<<dim3(4608), 256, 0, stream>>>(
      Xt, Wq, qkv, (size_t)16384 * 192, 0, (size_t)576 * 16384, 16384, 4608);
  // depthwise 3x3 in-place + per-channel sum-of-squares
  dwconv_kernel<<<dim3(576, 4), 256, 0, stream>>>(qkv, w_dw, sq);
  // gram partials: 16 chunk-groups per (b,h), in-block wave reduction
  gram_kernel<<<dim3(16, 16), 256, 0, stream>>>(qkv, partial);
  // reduce + normalize + softmax + fold into projection
  softmax_weff_kernel<<<dim3(16), 256, 0, stream>>>(partial, sq, temp, w_proj,
                                                    Weff);
  // v section [b][192][16384] -> vT [b][16384][192]
  transpose_u16_kernel<<<dim3(256, 3, 4), 256, 0, stream>>>(
      qkv + (size_t)384 * 16384, vT, (size_t)576 * 16384, (size_t)16384 * 192,
      16384);
  // out[b][o][n] = sum_c2 vT[n][c2]*Weff[o][c2]  (M=16384x4, N=192, K=192)
  gemm_bt_kernel<false, 3><<<dim3(1536), 256, 0, stream>>>(
      vT, Weff, d_out, (size_t)16384 * 192, (size_t)192 * 192,
      (size_t)192 * 16384, 16384, 1536);
}

// Round 4
// 138.848 us; speedup vs baseline: 1.5003x; 1.0301x over previous
//
#include <hip/hip_runtime.h>

typedef unsigned short u16;
typedef float f32x4 __attribute__((ext_vector_type(4)));
typedef __bf16 bf16x8 __attribute__((ext_vector_type(8)));
typedef unsigned short u16x8 __attribute__((ext_vector_type(8)));
typedef unsigned short u16x4 __attribute__((ext_vector_type(4)));

#define DEV static __device__ __forceinline__

DEV u16 f2bf(float f) {
  unsigned int u = __float_as_uint(f);
  u += 0x7FFFu + ((u >> 16) & 1u);   // round-to-nearest-even
  return (u16)(u >> 16);
}
DEV float bf2f(u16 h) { return __uint_as_float(((unsigned int)h) << 16); }

// async global->LDS, 16B per lane. LDS dest = wave-uniform base + lane*16.
DEV void gload_lds16(const void* g, void* l) {
  __builtin_amdgcn_global_load_lds(
      (__attribute__((address_space(1))) void*)(unsigned long long)g,
      (__attribute__((address_space(3))) void*)l, 16, 0, 0);
}

// ---------------------------------------------------------------------------
// K0b: convert w_qkv fp32 -> bf16
__global__ __launch_bounds__(256) void convert_w_kernel(
    const float* __restrict__ in, u16* __restrict__ out, int n) {
  int i = blockIdx.x * 256 + threadIdx.x;
  if (i < n) out[i] = f2bf(in[i]);
}

// ---------------------------------------------------------------------------
// Transpose [R=192][C=16384] fp32 -> bf16 [C][192], per batch. 64x64 tiles.
__global__ __launch_bounds__(256) void transpose_f32_kernel(
    const float* __restrict__ in, u16* __restrict__ out,
    size_t inBatch, size_t outBatch, int C) {
  __shared__ u16 ls[64][66];  // pad 66: column reads 2-way (free)
  const int b = blockIdx.z;
  const int c0 = blockIdx.x * 64, r0 = blockIdx.y * 64;
  const float* ip = in + (size_t)b * inBatch;
  u16* op = out + (size_t)b * outBatch;
  const int t = threadIdx.x;
  const int rr = t >> 4, cg = t & 15;  // 16 rows x 16 col-groups per pass
#pragma unroll
  for (int i = 0; i < 4; ++i) {
    const int r = i * 16 + rr;
    const f32x4 v = *(const f32x4*)(ip + (size_t)(r0 + r) * C + c0 + cg * 4);
    ls[r][cg * 4 + 0] = f2bf(v.x);
    ls[r][cg * 4 + 1] = f2bf(v.y);
    ls[r][cg * 4 + 2] = f2bf(v.z);
    ls[r][cg * 4 + 3] = f2bf(v.w);
  }
  __syncthreads();
  const int lane = t & 63, w = t >> 6;
#pragma unroll
  for (int i = 0; i < 16; ++i) {
    const int c = i * 4 + w;
    op[(size_t)(c0 + c) * 192 + r0 + lane] = ls[lane][c];
  }
}

// bf16 variant (v-path). Input u16x8 (16 B/lane).
__global__ __launch_bounds__(256) void transpose_u16_kernel(
    const u16* __restrict__ in, u16* __restrict__ out,
    size_t inBatch, size_t outBatch, int C) {
  __shared__ u16 ls[64][66];
  const int b = blockIdx.z;
  const int c0 = blockIdx.x * 64, r0 = blockIdx.y * 64;
  const u16* ip = in + (size_t)b * inBatch;
  u16* op = out + (size_t)b * outBatch;
  const int t = threadIdx.x;
  const int rr = t >> 3, cg = t & 7;  // 32 rows x 8 col-groups per pass
#pragma unroll
  for (int i = 0; i < 2; ++i) {
    const int r = i * 32 + rr;
    const u16x8 v = *(const u16x8*)(ip + (size_t)(r0 + r) * C + c0 + cg * 8);
#pragma unroll
    for (int j = 0; j < 8; ++j) ls[r][cg * 8 + j] = v[j];
  }
  __syncthreads();
  const int lane = t & 63, w = t >> 6;
#pragma unroll
  for (int i = 0; i < 16; ++i) {
    const int c = i * 4 + w;
    op[(size_t)(c0 + c) * 192 + r0 + lane] = ls[lane][c];
  }
}

// ---------------------------------------------------------------------------
// B^T GEMM, j-loop version. C[j][m] = sum_k A[m][k]*B[j][k], K=192.
// One block per 128-row A-panel (grid = 128 mtiles x 4 batches). A staged
// once (swizzled), fragments hoisted to registers; loop over NJ 64-col
// B-tiles through a single 24 KB LDS buffer, register-pipelined:
//   store acc(j-1) | read B_j frags | lgkm+bar | prefetch B_{j+1} | MFMA
//   | vmcnt(0)+bar
// Direct global stores from acc (no sC restage). 4 waves (2m x 2n).
template <bool OUT_BF16, int NJ>
__global__ __launch_bounds__(256, 2) void gemm_bt_kernel(
    const u16* __restrict__ A, const u16* __restrict__ B, void* __restrict__ Cv,
    size_t aBatch, size_t bBatch, size_t cBatch, int ldC) {
  __shared__ __align__(16) char smem[73728];
  char* sA = smem;            // [128][192] bf16, content-swizzled
  char* sB = smem + 49152;    // [64][192]  bf16, content-swizzled

  const int tid = threadIdx.x, wave = tid >> 6, lane = tid & 63;
  const int id = blockIdx.x;
  const int m0 = (id & 127) * 128, b = id >> 7;
  const char* Ab = (const char*)(A + (size_t)b * aBatch + (size_t)m0 * 192);
  const char* Bbase = (const char*)(B + (size_t)b * bBatch);

  // ---- stage A (48 KB, 12 chunks/wave) + B_0 (24 KB, 6 chunks/wave)
#pragma unroll
  for (int i = 0; i < 12; ++i) {
    const int c = i * 4 + wave;
    const int d = c * 1024 + lane * 16;
    const int row = d / 384, inrow = d - row * 384;
    gload_lds16(Ab + row * 384 + (inrow ^ ((row & 7) << 4)), sA + c * 1024);
  }
#pragma unroll
  for (int i = 0; i < 6; ++i) {
    const int c = i * 4 + wave;
    const int d = c * 1024 + lane * 16;
    const int row = d / 384, inrow = d - row * 384;
    gload_lds16(Bbase + row * 384 + (inrow ^ ((row & 7) << 4)), sB + c * 1024);
  }
  asm volatile("s_waitcnt vmcnt(0)" ::: "memory");
  __builtin_amdgcn_s_barrier();

  const int wm = wave & 1, wn = wave >> 1;
  const int l15 = lane & 15, lg = lane >> 4;
  const int swm = (l15 & 7) << 4;  // row&7 == l15&7 for all fragment rows
  const int rA0 = (wm * 64 + l15) * 384;
  const int rB0 = (wn * 32 + l15) * 384;

  // ---- A fragments to registers once (96 VGPR), reused for all j
  bf16x8 af[4][6];
#pragma unroll
  for (int mi = 0; mi < 4; ++mi)
#pragma unroll
    for (int ks = 0; ks < 6; ++ks)
      af[mi][ks] = *(const bf16x8*)(sA + rA0 + mi * 16 * 384 +
                                    ((ks * 64 + lg * 16) ^ swm));

  f32x4 acc[4][2];
  for (int j = 0; j < NJ; ++j) {
    // store previous tile (issued early -> full MFMA phase of slack)
    if (j > 0) {
      const int j0 = (j - 1) * 64;
      if (OUT_BF16) {
        u16* Cb = (u16*)Cv + (size_t)b * cBatch;
#pragma unroll
        for (int mi = 0; mi < 4; ++mi)
#pragma unroll
          for (int nj = 0; nj < 2; ++nj) {
            u16x4 ov;
#pragma unroll
            for (int r = 0; r < 4; ++r) ov[r] = f2bf(acc[mi][nj][r]);
            *(u16x4*)(Cb + (size_t)(j0 + wn * 32 + nj * 16 + l15) * ldC + m0 +
                      wm * 64 + mi * 16 + lg * 4) = ov;
          }
      } else {
        float* Cb = (float*)Cv + (size_t)b * cBatch;
#pragma unroll
        for (int mi = 0; mi < 4; ++mi)
#pragma unroll
          for (int nj = 0; nj < 2; ++nj)
            *(f32x4*)(Cb + (size_t)(j0 + wn * 32 + nj * 16 + l15) * ldC + m0 +
                      wm * 64 + mi * 16 + lg * 4) = acc[mi][nj];
      }
    }
    // read B_j fragments (48 VGPR)
    bf16x8 bfv[2][6];
#pragma unroll
    for (int nj = 0; nj < 2; ++nj)
#pragma unroll
      for (int ks = 0; ks < 6; ++ks)
        bfv[nj][ks] = *(const bf16x8*)(sB + rB0 + nj * 16 * 384 +
                                       ((ks * 64 + lg * 16) ^ swm));
    asm volatile("s_waitcnt lgkmcnt(0)" ::: "memory");
    __builtin_amdgcn_s_barrier();  // all waves consumed sB -> overwritable
    if (j + 1 < NJ) {
      const char* Bj = Bbase + (size_t)(j + 1) * 64 * 384;
#pragma unroll
      for (int i = 0; i < 6; ++i) {
        const int c = i * 4 + wave;
        const int d = c * 1024 + lane * 16;
        const int row = d / 384, inrow = d - row * 384;
        gload_lds16(Bj + row * 384 + (inrow ^ ((row & 7) << 4)), sB + c * 1024);
      }
    }
    __builtin_amdgcn_sched_barrier(0);  // pin: prefetch issued before MFMA
#pragma unroll
    for (int mi = 0; mi < 4; ++mi)
#pragma unroll
      for (int nj = 0; nj < 2; ++nj) acc[mi][nj] = (f32x4){0.f, 0.f, 0.f, 0.f};
#pragma unroll
    for (int ks = 0; ks < 6; ++ks)
#pragma unroll
      for (int mi = 0; mi < 4; ++mi)
#pragma unroll
        for (int nj = 0; nj < 2; ++nj)
          acc[mi][nj] = __builtin_amdgcn_mfma_f32_16x16x32_bf16(
              af[mi][ks], bfv[nj][ks], acc[mi][nj], 0, 0, 0);
    if (j + 1 < NJ) {
      asm volatile("s_waitcnt vmcnt(0)" ::: "memory");  // B_{j+1} landed
      __builtin_amdgcn_s_barrier();
    }
  }
  // final tile store
  {
    const int j0 = (NJ - 1) * 64;
    if (OUT_BF16) {
      u16* Cb = (u16*)Cv + (size_t)b * cBatch;
#pragma unroll
      for (int mi = 0; mi < 4; ++mi)
#pragma unroll
        for (int nj = 0; nj < 2; ++nj) {
          u16x4 ov;
#pragma unroll
          for (int r = 0; r < 4; ++r) ov[r] = f2bf(acc[mi][nj][r]);
          *(u16x4*)(Cb + (size_t)(j0 + wn * 32 + nj * 16 + l15) * ldC + m0 +
                    wm * 64 + mi * 16 + lg * 4) = ov;
        }
    } else {
      float* Cb = (float*)Cv + (size_t)b * cBatch;
#pragma unroll
      for (int mi = 0; mi < 4; ++mi)
#pragma unroll
        for (int nj = 0; nj < 2; ++nj)
          *(f32x4*)(Cb + (size_t)(j0 + wn * 32 + nj * 16 + l15) * ldC + m0 +
                    wm * 64 + mi * 16 + lg * 4) = acc[mi][nj];
    }
  }
}

// ---------------------------------------------------------------------------
// Depthwise 3x3 (pad 1), in-place on bf16 [b][576][128][128]; per-channel
// sum-of-squares for the q/k L2 norms. One block per (b, channel).
__global__ __launch_bounds__(256) void dwconv_kernel(
    u16* __restrict__ qkv, const float* __restrict__ wdw,
    float* __restrict__ sq) {
  __shared__ u16 img[16384];  // full 128x128 channel, 32 KB
  __shared__ float red[4];
  const int o = blockIdx.x, b = blockIdx.y;
  const size_t base = ((size_t)b * 576 + o) * 16384;
  const int tid = threadIdx.x, wave = tid >> 6, lane = tid & 63;
#pragma unroll
  for (int i = 0; i < 8; ++i) {
    const int off = (i * 4 + wave) * 1024;
    gload_lds16((const char*)qkv + base * 2 + off + lane * 16, (char*)img + off);
  }
  asm volatile("s_waitcnt vmcnt(0)" ::: "memory");
  __syncthreads();
  float w[9];
#pragma unroll
  for (int j = 0; j < 9; ++j) w[j] = wdw[o * 9 + j];
  float sqacc = 0.f;
  for (int it = 0; it < 8; ++it) {
    const int chunk = it * 256 + tid;  // 2048 chunks of 8 px
    const int px0 = chunk * 8;
    const int y = px0 >> 7, x0 = px0 & 127;
    float acc[8];
#pragma unroll
    for (int j = 0; j < 8; ++j) acc[j] = 0.f;
#pragma unroll
    for (int dy = -1; dy <= 1; ++dy) {
      const int yy = y + dy;
      float v[10];
      if (yy >= 0 && yy <= 127) {
        const u16* rowp = img + yy * 128 + x0;
        u16x8 m = *(const u16x8*)rowp;
#pragma unroll
        for (int j = 0; j < 8; ++j) v[j + 1] = bf2f(m[j]);
        v[0] = (x0 > 0) ? bf2f(rowp[-1]) : 0.f;
        v[9] = (x0 < 120) ? bf2f(rowp[8]) : 0.f;
      } else {
#pragma unroll
        for (int j = 0; j < 10; ++j) v[j] = 0.f;
      }
      const float w0 = w[(dy + 1) * 3], w1 = w[(dy + 1) * 3 + 1],
                  w2 = w[(dy + 1) * 3 + 2];
#pragma unroll
      for (int j = 0; j < 8; ++j) acc[j] += w0 * v[j] + w1 * v[j + 1] + w2 * v[j + 2];
    }
    u16x8 ov;
#pragma unroll
    for (int j = 0; j < 8; ++j) {
      sqacc += acc[j] * acc[j];
      ov[j] = f2bf(acc[j]);
    }
    *(u16x8*)(qkv + base + px0) = ov;  // in-place: all reads came from LDS
  }
#pragma unroll
  for (int s = 32; s > 0; s >>= 1) sqacc += __shfl_xor(sqacc, s, 64);
  if (lane == 0) red[wave] = sqacc;
  __syncthreads();
  if (tid == 0) sq[b * 576 + o] = red[0] + red[1] + red[2] + red[3];
}

// ---------------------------------------------------------------------------
// Gram: G_partial[c][d] = sum_n q[c][n]*k[d][n] over a 1024-n block (4 waves x
// 256 n each, reduced in-block through LDS). Tile content XOR-swizzled
// ((row&3)<<4 within 64-B rows) via pre-swizzled global source -> frag
// ds_read_b128 conflict-free (was 8-way).
__global__ __launch_bounds__(256) void gram_kernel(
    const u16* __restrict__ qkv, float* __restrict__ partial) {
  __shared__ u16 tiles[4 * 3072];   // per-wave [96][32] bf16 (q 0-47, k 48-95)
  __shared__ float red[4 * 2304];   // per-wave gram copies for in-block reduce
  const int bh = blockIdx.y, b = bh >> 2, h = bh & 3;
  const int g = blockIdx.x;                  // chunk-group 0..15
  const int wave = threadIdx.x >> 6, lane = threadIdx.x & 63;
  const int n0 = g * 1024 + wave * 256;
  const u16* qb = qkv + ((size_t)b * 576 + h * 48) * 16384;
  const u16* kb = qb + (size_t)192 * 16384;
  char* tl = (char*)(tiles + wave * 3072);
  const int l15 = lane & 15, lg = lane >> 4;
  const int swz = (l15 & 3) << 4;
  f32x4 acc[3][3];
#pragma unroll
  for (int i = 0; i < 3; ++i)
#pragma unroll
    for (int j = 0; j < 3; ++j) acc[i][j] = (f32x4){0.f, 0.f, 0.f, 0.f};

  for (int ks = 0; ks < 8; ++ks) {
    const int nn = n0 + ks * 32;
    asm volatile("s_waitcnt lgkmcnt(0)" ::: "memory");
#pragma unroll
    for (int i = 0; i < 6; ++i) {
      const int flat = i * 1024 + lane * 16;
      const int row = flat >> 6, colb = flat & 63;
      const u16* src = (row < 48) ? (qb + (size_t)row * 16384 + nn)
                                  : (kb + (size_t)(row - 48) * 16384 + nn);
      gload_lds16((const char*)src + (colb ^ ((row & 3) << 4)), tl + i * 1024);
    }
    asm volatile("s_waitcnt vmcnt(0)" ::: "memory");
    bf16x8 qf[3], kf[3];
#pragma unroll
    for (int f = 0; f < 3; ++f) {
      qf[f] = *(const bf16x8*)(tl + (f * 16 + l15) * 64 + ((lg * 16) ^ swz));
      kf[f] = *(const bf16x8*)(tl + (48 + f * 16 + l15) * 64 + ((lg * 16) ^ swz));
    }
#pragma unroll
    for (int i = 0; i < 3; ++i)
#pragma unroll
      for (int j = 0; j < 3; ++j)
        acc[i][j] = __builtin_amdgcn_mfma_f32_16x16x32_bf16(qf[i], kf[j],
                                                            acc[i][j], 0, 0, 0);
  }
  // in-block reduce over the 4 waves
  {
    float* rw = red + wave * 2304;
#pragma unroll
    for (int i = 0; i < 3; ++i)
#pragma unroll
      for (int j = 0; j < 3; ++j)
#pragma unroll
        for (int r = 0; r < 4; ++r)
          rw[(i * 16 + lg * 4 + r) * 48 + (j * 16 + l15)] = acc[i][j][r];
  }
  __syncthreads();
#pragma unroll
  for (int it = 0; it < 9; ++it) {
    const int p = it * 256 + threadIdx.x;
    const float s = red[p] + red[2304 + p] + red[4608 + p] + red[6912 + p];
    partial[((size_t)bh * 2304 + p) * 16 + g] = s;
  }
}

// ---------------------------------------------------------------------------
// Stage 2: reduce 16 chunks, normalize, softmax, fold attn into projection.
__global__ __launch_bounds__(256) void softmax_weff_kernel(
    const float* __restrict__ partial, const float* __restrict__ sq,
    const float* __restrict__ temp, const float* __restrict__ wproj,
    u16* __restrict__ weff) {
  __shared__ float G[2304];        // gram -> attn (in place)
  __shared__ float wp[192 * 49];   // wproj slice, pad 49 (odd bank stride)
  __shared__ float nq[48], nk[48];
  const int bh = blockIdx.x, b = bh >> 2, h = bh & 3;
  const int tid = threadIdx.x;
#pragma unroll
  for (int it = 0; it < 36; ++it) {  // load wproj [192][h*48 .. h*48+48)
    const int j = it * 256 + tid;
    const int o = j / 48, c = j - o * 48;
    wp[o * 49 + c] = wproj[o * 192 + h * 48 + c];
  }
#pragma unroll
  for (int it = 0; it < 9; ++it) {   // reduce 16 partial chunks, coalesced
    const int p = it * 256 + tid;
    const f32x4* pp = (const f32x4*)(partial + ((size_t)bh * 2304 + p) * 16);
    const f32x4 a = pp[0] + pp[1] + pp[2] + pp[3];
    G[p] = a.x + a.y + a.z + a.w;
  }
  if (tid < 48) {
    nq[tid] = fmaxf(sqrtf(sq[b * 576 + h * 48 + tid]), 1e-12f);
    nk[tid] = fmaxf(sqrtf(sq[b * 576 + 192 + h * 48 + tid]), 1e-12f);
  }
  __syncthreads();
  if (tid < 48) {  // row softmax (48 rows)
    const int r = tid;
    const float inq = temp[h] / nq[r];
    float L[48];
    float mx = -3.4e38f;
#pragma unroll 4
    for (int d = 0; d < 48; ++d) {
      const float v = G[r * 48 + d] * inq / nk[d];
      L[d] = v;
      mx = fmaxf(mx, v);
    }
    float s = 0.f;
#pragma unroll 4
    for (int d = 0; d < 48; ++d) {
      const float e = __expf(L[d] - mx);
      L[d] = e;
      s += e;
    }
    const float inv = 1.f / s;
#pragma unroll 4
    for (int d = 0; d < 48; ++d) G[r * 48 + d] = L[d] * inv;
  }
  __syncthreads();
  if (tid < 192) {  // Weff row o = tid
    const int o = tid;
    f32x4 acc[12];
#pragma unroll
    for (int dv = 0; dv < 12; ++dv) acc[dv] = (f32x4){0.f, 0.f, 0.f, 0.f};
    for (int c = 0; c < 48; ++c) {
      const float w = wp[o * 49 + c];
      const f32x4* at = (const f32x4*)(G + c * 48);  // broadcast reads
#pragma unroll
      for (int dv = 0; dv < 12; ++dv) acc[dv] += w * at[dv];
    }
    u16* op = weff + ((size_t)b * 192 + o) * 192 + h * 48;
#pragma unroll
    for (int g8 = 0; g8 < 6; ++g8) {
      u16x8 ov;
#pragma unroll
      for (int j = 0; j < 8; ++j) {
        const int d = g8 * 8 + j;
        ov[j] = f2bf(acc[d >> 2][d & 3]);
      }
      *(u16x8*)(op + g8 * 8) = ov;
    }
  }
}

// ---------------------------------------------------------------------------
extern "C" void kernel_launch(void* const* d_in, const int* in_sizes, int n_in,
                              void* d_out, int out_size, void* d_ws,
                              size_t ws_size, hipStream_t stream) {
  (void)in_sizes; (void)n_in; (void)out_size; (void)ws_size;
  const float* x      = (const float*)d_in[0];  // [4][192][128][128]
  const float* w_qkv  = (const float*)d_in[1];  // [576][192]
  const float* w_dw   = (const float*)d_in[2];  // [576][9]
  const float* w_proj = (const float*)d_in[3];  // [192][192]
  const float* temp   = (const float*)d_in[4];  // [4]

  char* ws = (char*)d_ws;
  u16*   qkv     = (u16*)ws;                    // 75,497,472 B
  u16*   vT      = (u16*)(ws + 75497472);       // 25,165,824 B
  float* partial = (float*)(ws + 100663296);    //  2,359,296 B  [16][2304][16]
  float* sq      = (float*)(ws + 103022592);    //      9,216 B
  u16*   Wq      = (u16*)(ws + 103031808);      //    221,184 B
  u16*   Weff    = (u16*)(ws + 103252992);      //    294,912 B
  u16*   Xt      = (u16*)d_out;                 // 25.2 MB scratch, dead before final GEMM

  // w_qkv -> bf16
  convert_w_kernel<<<dim3(432), 256, 0, stream>>>(w_qkv, Wq, 110592);
  // x [b][192][16384] -> Xt [b][16384][192] bf16
  transpose_f32_kernel<<<dim3(256, 3, 4), 256, 0, stream>>>(
      x, Xt, (size_t)192 * 16384, (size_t)16384 * 192, 16384);
  // qkv[b][o][n] = sum_c Xt[n][c]*Wq[o][c]   (M=16384x4, N=576, K=192)
  gemm_bt_kernel<true, 9><<<dim3(512), 256, 0, stream>>>(
      Xt, Wq, qkv, (size_t)16384 * 192, 0, (size_t)576 * 16384, 16384);
  // depthwise 3x3 in-place + per-channel sum-of-squares
  dwconv_kernel<<<dim3(576, 4), 256, 0, stream>>>(qkv, w_dw, sq);
  // gram partials: 16 chunk-groups per (b,h), in-block wave reduction
  gram_kernel<<<dim3(16, 16), 256, 0, stream>>>(qkv, partial);
  // reduce + normalize + softmax + fold into projection
  softmax_weff_kernel<<<dim3(16), 256, 0, stream>>>(partial, sq, temp, w_proj,
                                                    Weff);
  // v section [b][192][16384] -> vT [b][16384][192]
  transpose_u16_kernel<<<dim3(256, 3, 4), 256, 0, stream>>>(
      qkv + (size_t)384 * 16384, vT, (size_t)576 * 16384, (size_t)16384 * 192,
      16384);
  // out[b][o][n] = sum_c2 vT[n][c2]*Weff[o][c2]  (M=16384x4, N=192, K=192)
  gemm_bt_kernel<false, 3><<<dim3(512), 256, 0, stream>>>(
      vT, Weff, d_out, (size_t)16384 * 192, (size_t)192 * 192,
      (size_t)192 * 16384, 16384);
}

// Round 5
// 137.259 us; speedup vs baseline: 1.5177x; 1.0116x over previous
//
#include <hip/hip_runtime.h>

typedef unsigned short u16;
typedef float f32x4 __attribute__((ext_vector_type(4)));
typedef __bf16 bf16x8 __attribute__((ext_vector_type(8)));
typedef unsigned short u16x8 __attribute__((ext_vector_type(8)));
typedef unsigned short u16x4 __attribute__((ext_vector_type(4)));

#define DEV static __device__ __forceinline__

DEV u16 f2bf(float f) {
  unsigned int u = __float_as_uint(f);
  u += 0x7FFFu + ((u >> 16) & 1u);   // round-to-nearest-even
  return (u16)(u >> 16);
}
DEV float bf2f(u16 h) { return __uint_as_float(((unsigned int)h) << 16); }

// async global->LDS, 16B per lane. LDS dest = wave-uniform base + lane*16.
DEV void gload_lds16(const void* g, void* l) {
  __builtin_amdgcn_global_load_lds(
      (__attribute__((address_space(1))) void*)(unsigned long long)g,
      (__attribute__((address_space(3))) void*)l, 16, 0, 0);
}

// ---------------------------------------------------------------------------
// K0b: convert w_qkv fp32 -> bf16
__global__ __launch_bounds__(256) void convert_w_kernel(
    const float* __restrict__ in, u16* __restrict__ out, int n) {
  int i = blockIdx.x * 256 + threadIdx.x;
  if (i < n) out[i] = f2bf(in[i]);
}

// ---------------------------------------------------------------------------
// B^T GEMM with FUSED A-transpose. C[j][m] = sum_k A^T[m][k]*B[j][k], K=192.
// A source is channel-planar [192][16384] (fp32 x, or bf16 v); each block
// owns 128 consecutive pixels (m), stages A-tile [128 m][192 c] bf16 into
// LDS via register 4x4/4x8 transpose + convert, written at the same
// XOR-swizzled addresses ((c2)^((n&7)<<4)) the fragment reads use.
// Then j-loop over NJ 64-col B-tiles (single 24 KB buffer, reg-pipelined):
//   store acc(j-1) | read B_j frags | lgkm+bar | prefetch B_{j+1} | MFMA
//   | vmcnt+bar
// 4 waves (2m x 2n). Direct global stores from acc.
template <bool IN_F32, bool OUT_BF16, int NJ>
__global__ __launch_bounds__(256, 2) void gemm_bt_kernel(
    const void* __restrict__ Av, const u16* __restrict__ B,
    void* __restrict__ Cv, size_t aBatch, size_t bBatch, size_t cBatch,
    int ldC) {
  __shared__ __align__(16) char smem[73728];
  char* sA = smem;            // [128][192] bf16, content-swizzled (48 KB)
  char* sB = smem + 49152;    // [64][192]  bf16, content-swizzled (24 KB)

  const int tid = threadIdx.x, wave = tid >> 6, lane = tid & 63;
  const int id = blockIdx.x;
  const int m0 = (id & 127) * 128, b = id >> 7;

  // ---- A-staging: fused transpose (+convert). Writes u16x4 (8 B) of a
  // c-quad at row n, byte (cb*8)^((n&7)<<4) — bit-exact with frag reads.
  if (IN_F32) {
    const float* Xb = (const float*)Av + (size_t)b * aBatch + m0;
    const int cbl = tid & 7, iq = tid >> 3;  // 8 c-quads x 32 n-quads
#pragma unroll
    for (int pass = 0; pass < 6; ++pass) {
      const int cb = pass * 8 + cbl;
      f32x4 v[4];
#pragma unroll
      for (int r = 0; r < 4; ++r)
        v[r] = *(const f32x4*)(Xb + (size_t)(cb * 4 + r) * 16384 + iq * 4);
#pragma unroll
      for (int j = 0; j < 4; ++j) {
        const int n = iq * 4 + j;
        u16x4 col;
        col[0] = f2bf(v[0][j]);
        col[1] = f2bf(v[1][j]);
        col[2] = f2bf(v[2][j]);
        col[3] = f2bf(v[3][j]);
        *(u16x4*)(sA + n * 384 + ((cb * 8) ^ ((n & 7) << 4))) = col;
      }
    }
  } else {
    const u16* Vb = (const u16*)Av + (size_t)b * aBatch + m0;
    const int cbl = tid & 15, iq = tid >> 4;  // 16 c-quads x 16 n-octs
#pragma unroll
    for (int pass = 0; pass < 3; ++pass) {
      const int cb = pass * 16 + cbl;
      u16x8 v[4];
#pragma unroll
      for (int r = 0; r < 4; ++r)
        v[r] = *(const u16x8*)(Vb + (size_t)(cb * 4 + r) * 16384 + iq * 8);
#pragma unroll
      for (int j = 0; j < 8; ++j) {
        const int n = iq * 8 + j;
        u16x4 col;
        col[0] = v[0][j];
        col[1] = v[1][j];
        col[2] = v[2][j];
        col[3] = v[3][j];
        *(u16x4*)(sA + n * 384 + ((cb * 8) ^ ((n & 7) << 4))) = col;
      }
    }
  }
  // ---- stage B_0 (24 KB, 6 chunks/wave) via gload_lds
  const char* Bbase = (const char*)(B + (size_t)b * bBatch);
#pragma unroll
  for (int i = 0; i < 6; ++i) {
    const int c = i * 4 + wave;
    const int d = c * 1024 + lane * 16;
    const int row = d / 384, inrow = d - row * 384;
    gload_lds16(Bbase + row * 384 + (inrow ^ ((row & 7) << 4)), sB + c * 1024);
  }
  asm volatile("s_waitcnt vmcnt(0) lgkmcnt(0)" ::: "memory");
  __builtin_amdgcn_s_barrier();

  const int wm = wave & 1, wn = wave >> 1;
  const int l15 = lane & 15, lg = lane >> 4;
  const int swm = (l15 & 7) << 4;  // row&7 == l15&7 for all fragment rows
  const int rA0 = (wm * 64 + l15) * 384;
  const int rB0 = (wn * 32 + l15) * 384;

  // ---- A fragments to registers, reused for all j
  bf16x8 af[4][6];
#pragma unroll
  for (int mi = 0; mi < 4; ++mi)
#pragma unroll
    for (int ks = 0; ks < 6; ++ks)
      af[mi][ks] = *(const bf16x8*)(sA + rA0 + mi * 16 * 384 +
                                    ((ks * 64 + lg * 16) ^ swm));

  f32x4 acc[4][2];
  for (int j = 0; j < NJ; ++j) {
    // store previous tile (issued early -> full MFMA phase of slack)
    if (j > 0) {
      const int j0 = (j - 1) * 64;
      if (OUT_BF16) {
        u16* Cb = (u16*)Cv + (size_t)b * cBatch;
#pragma unroll
        for (int mi = 0; mi < 4; ++mi)
#pragma unroll
          for (int nj = 0; nj < 2; ++nj) {
            u16x4 ov;
#pragma unroll
            for (int r = 0; r < 4; ++r) ov[r] = f2bf(acc[mi][nj][r]);
            *(u16x4*)(Cb + (size_t)(j0 + wn * 32 + nj * 16 + l15) * ldC + m0 +
                      wm * 64 + mi * 16 + lg * 4) = ov;
          }
      } else {
        float* Cb = (float*)Cv + (size_t)b * cBatch;
#pragma unroll
        for (int mi = 0; mi < 4; ++mi)
#pragma unroll
          for (int nj = 0; nj < 2; ++nj)
            *(f32x4*)(Cb + (size_t)(j0 + wn * 32 + nj * 16 + l15) * ldC + m0 +
                      wm * 64 + mi * 16 + lg * 4) = acc[mi][nj];
      }
    }
    // read B_j fragments
    bf16x8 bfv[2][6];
#pragma unroll
    for (int nj = 0; nj < 2; ++nj)
#pragma unroll
      for (int ks = 0; ks < 6; ++ks)
        bfv[nj][ks] = *(const bf16x8*)(sB + rB0 + nj * 16 * 384 +
                                       ((ks * 64 + lg * 16) ^ swm));
    asm volatile("s_waitcnt lgkmcnt(0)" ::: "memory");
    __builtin_amdgcn_s_barrier();  // all waves consumed sB -> overwritable
    if (j + 1 < NJ) {
      const char* Bj = Bbase + (size_t)(j + 1) * 64 * 384;
#pragma unroll
      for (int i = 0; i < 6; ++i) {
        const int c = i * 4 + wave;
        const int d = c * 1024 + lane * 16;
        const int row = d / 384, inrow = d - row * 384;
        gload_lds16(Bj + row * 384 + (inrow ^ ((row & 7) << 4)), sB + c * 1024);
      }
    }
    __builtin_amdgcn_sched_barrier(0);  // pin: prefetch issued before MFMA
#pragma unroll
    for (int mi = 0; mi < 4; ++mi)
#pragma unroll
      for (int nj = 0; nj < 2; ++nj) acc[mi][nj] = (f32x4){0.f, 0.f, 0.f, 0.f};
#pragma unroll
    for (int ks = 0; ks < 6; ++ks)
#pragma unroll
      for (int mi = 0; mi < 4; ++mi)
#pragma unroll
        for (int nj = 0; nj < 2; ++nj)
          acc[mi][nj] = __builtin_amdgcn_mfma_f32_16x16x32_bf16(
              af[mi][ks], bfv[nj][ks], acc[mi][nj], 0, 0, 0);
    if (j + 1 < NJ) {
      asm volatile("s_waitcnt vmcnt(0)" ::: "memory");  // B_{j+1} landed
      __builtin_amdgcn_s_barrier();
    }
  }
  // final tile store
  {
    const int j0 = (NJ - 1) * 64;
    if (OUT_BF16) {
      u16* Cb = (u16*)Cv + (size_t)b * cBatch;
#pragma unroll
      for (int mi = 0; mi < 4; ++mi)
#pragma unroll
        for (int nj = 0; nj < 2; ++nj) {
          u16x4 ov;
#pragma unroll
          for (int r = 0; r < 4; ++r) ov[r] = f2bf(acc[mi][nj][r]);
          *(u16x4*)(Cb + (size_t)(j0 + wn * 32 + nj * 16 + l15) * ldC + m0 +
                    wm * 64 + mi * 16 + lg * 4) = ov;
        }
    } else {
      float* Cb = (float*)Cv + (size_t)b * cBatch;
#pragma unroll
      for (int mi = 0; mi < 4; ++mi)
#pragma unroll
        for (int nj = 0; nj < 2; ++nj)
          *(f32x4*)(Cb + (size_t)(j0 + wn * 32 + nj * 16 + l15) * ldC + m0 +
                    wm * 64 + mi * 16 + lg * 4) = acc[mi][nj];
    }
  }
}

// ---------------------------------------------------------------------------
// Depthwise 3x3 (pad 1), in-place on bf16 [b][576][128][128]; per-channel
// sum-of-squares for the q/k L2 norms. One block per (b, channel).
__global__ __launch_bounds__(256) void dwconv_kernel(
    u16* __restrict__ qkv, const float* __restrict__ wdw,
    float* __restrict__ sq) {
  __shared__ u16 img[16384];  // full 128x128 channel, 32 KB
  __shared__ float red[4];
  const int o = blockIdx.x, b = blockIdx.y;
  const size_t base = ((size_t)b * 576 + o) * 16384;
  const int tid = threadIdx.x, wave = tid >> 6, lane = tid & 63;
#pragma unroll
  for (int i = 0; i < 8; ++i) {
    const int off = (i * 4 + wave) * 1024;
    gload_lds16((const char*)qkv + base * 2 + off + lane * 16, (char*)img + off);
  }
  asm volatile("s_waitcnt vmcnt(0)" ::: "memory");
  __syncthreads();
  float w[9];
#pragma unroll
  for (int j = 0; j < 9; ++j) w[j] = wdw[o * 9 + j];
  float sqacc = 0.f;
  for (int it = 0; it < 8; ++it) {
    const int chunk = it * 256 + tid;  // 2048 chunks of 8 px
    const int px0 = chunk * 8;
    const int y = px0 >> 7, x0 = px0 & 127;
    float acc[8];
#pragma unroll
    for (int j = 0; j < 8; ++j) acc[j] = 0.f;
#pragma unroll
    for (int dy = -1; dy <= 1; ++dy) {
      const int yy = y + dy;
      float v[10];
      if (yy >= 0 && yy <= 127) {
        const u16* rowp = img + yy * 128 + x0;
        u16x8 m = *(const u16x8*)rowp;
#pragma unroll
        for (int j = 0; j < 8; ++j) v[j + 1] = bf2f(m[j]);
        v[0] = (x0 > 0) ? bf2f(rowp[-1]) : 0.f;
        v[9] = (x0 < 120) ? bf2f(rowp[8]) : 0.f;
      } else {
#pragma unroll
        for (int j = 0; j < 10; ++j) v[j] = 0.f;
      }
      const float w0 = w[(dy + 1) * 3], w1 = w[(dy + 1) * 3 + 1],
                  w2 = w[(dy + 1) * 3 + 2];
#pragma unroll
      for (int j = 0; j < 8; ++j) acc[j] += w0 * v[j] + w1 * v[j + 1] + w2 * v[j + 2];
    }
    u16x8 ov;
#pragma unroll
    for (int j = 0; j < 8; ++j) {
      sqacc += acc[j] * acc[j];
      ov[j] = f2bf(acc[j]);
    }
    *(u16x8*)(qkv + base + px0) = ov;  // in-place: all reads came from LDS
  }
#pragma unroll
  for (int s = 32; s > 0; s >>= 1) sqacc += __shfl_xor(sqacc, s, 64);
  if (lane == 0) red[wave] = sqacc;
  __syncthreads();
  if (tid == 0) sq[b * 576 + o] = red[0] + red[1] + red[2] + red[3];
}

// ---------------------------------------------------------------------------
// Gram: G_partial[c][d] = sum_n q[c][n]*k[d][n] over a 512-n block (4 waves x
// 128 n each, reduced in-block through LDS). Tile content XOR-swizzled
// ((row&3)<<4 in 64-B rows) via pre-swizzled source -> conflict-free reads.
// grid (32 chunk-groups, 16 bh); partial[bh][pos][chunk32].
__global__ __launch_bounds__(256) void gram_kernel(
    const u16* __restrict__ qkv, float* __restrict__ partial) {
  __shared__ u16 tiles[4 * 3072];   // per-wave [96][32] bf16 (q 0-47, k 48-95)
  __shared__ float red[4 * 2304];   // per-wave gram copies for in-block reduce
  const int bh = blockIdx.y, b = bh >> 2, h = bh & 3;
  const int g = blockIdx.x;                  // chunk 0..31
  const int wave = threadIdx.x >> 6, lane = threadIdx.x & 63;
  const int n0 = g * 512 + wave * 128;
  const u16* qb = qkv + ((size_t)b * 576 + h * 48) * 16384;
  const u16* kb = qb + (size_t)192 * 16384;
  char* tl = (char*)(tiles + wave * 3072);
  const int l15 = lane & 15, lg = lane >> 4;
  const int swz = (l15 & 3) << 4;
  f32x4 acc[3][3];
#pragma unroll
  for (int i = 0; i < 3; ++i)
#pragma unroll
    for (int j = 0; j < 3; ++j) acc[i][j] = (f32x4){0.f, 0.f, 0.f, 0.f};

  for (int ks = 0; ks < 4; ++ks) {
    const int nn = n0 + ks * 32;
    asm volatile("s_waitcnt lgkmcnt(0)" ::: "memory");
#pragma unroll
    for (int i = 0; i < 6; ++i) {
      const int flat = i * 1024 + lane * 16;
      const int row = flat >> 6, colb = flat & 63;
      const u16* src = (row < 48) ? (qb + (size_t)row * 16384 + nn)
                                  : (kb + (size_t)(row - 48) * 16384 + nn);
      gload_lds16((const char*)src + (colb ^ ((row & 3) << 4)), tl + i * 1024);
    }
    asm volatile("s_waitcnt vmcnt(0)" ::: "memory");
    bf16x8 qf[3], kf[3];
#pragma unroll
    for (int f = 0; f < 3; ++f) {
      qf[f] = *(const bf16x8*)(tl + (f * 16 + l15) * 64 + ((lg * 16) ^ swz));
      kf[f] = *(const bf16x8*)(tl + (48 + f * 16 + l15) * 64 + ((lg * 16) ^ swz));
    }
#pragma unroll
    for (int i = 0; i < 3; ++i)
#pragma unroll
      for (int j = 0; j < 3; ++j)
        acc[i][j] = __builtin_amdgcn_mfma_f32_16x16x32_bf16(qf[i], kf[j],
                                                            acc[i][j], 0, 0, 0);
  }
  // in-block reduce over the 4 waves
  {
    float* rw = red + wave * 2304;
#pragma unroll
    for (int i = 0; i < 3; ++i)
#pragma unroll
      for (int j = 0; j < 3; ++j)
#pragma unroll
        for (int r = 0; r < 4; ++r)
          rw[(i * 16 + lg * 4 + r) * 48 + (j * 16 + l15)] = acc[i][j][r];
  }
  __syncthreads();
#pragma unroll
  for (int it = 0; it < 9; ++it) {
    const int p = it * 256 + threadIdx.x;
    const float s = red[p] + red[2304 + p] + red[4608 + p] + red[6912 + p];
    partial[((size_t)bh * 2304 + p) * 32 + g] = s;
  }
}

// ---------------------------------------------------------------------------
// Stage 2: reduce 32 chunks, normalize, softmax, fold attn into projection.
__global__ __launch_bounds__(256) void softmax_weff_kernel(
    const float* __restrict__ partial, const float* __restrict__ sq,
    const float* __restrict__ temp, const float* __restrict__ wproj,
    u16* __restrict__ weff) {
  __shared__ float G[2304];        // gram -> attn (in place)
  __shared__ float wp[192 * 49];   // wproj slice, pad 49 (odd bank stride)
  __shared__ float nq[48], nk[48];
  const int bh = blockIdx.x, b = bh >> 2, h = bh & 3;
  const int tid = threadIdx.x;
#pragma unroll
  for (int it = 0; it < 36; ++it) {  // load wproj [192][h*48 .. h*48+48)
    const int j = it * 256 + tid;
    const int o = j / 48, c = j - o * 48;
    wp[o * 49 + c] = wproj[o * 192 + h * 48 + c];
  }
#pragma unroll
  for (int it = 0; it < 9; ++it) {   // reduce 32 partial chunks, coalesced
    const int p = it * 256 + tid;
    const f32x4* pp = (const f32x4*)(partial + ((size_t)bh * 2304 + p) * 32);
    const f32x4 a = (pp[0] + pp[1]) + (pp[2] + pp[3]) +
                    (pp[4] + pp[5]) + (pp[6] + pp[7]);
    G[p] = a.x + a.y + a.z + a.w;
  }
  if (tid < 48) {
    nq[tid] = fmaxf(sqrtf(sq[b * 576 + h * 48 + tid]), 1e-12f);
    nk[tid] = fmaxf(sqrtf(sq[b * 576 + 192 + h * 48 + tid]), 1e-12f);
  }
  __syncthreads();
  if (tid < 48) {  // row softmax (48 rows)
    const int r = tid;
    const float inq = temp[h] / nq[r];
    float L[48];
    float mx = -3.4e38f;
#pragma unroll 4
    for (int d = 0; d < 48; ++d) {
      const float v = G[r * 48 + d] * inq / nk[d];
      L[d] = v;
      mx = fmaxf(mx, v);
    }
    float s = 0.f;
#pragma unroll 4
    for (int d = 0; d < 48; ++d) {
      const float e = __expf(L[d] - mx);
      L[d] = e;
      s += e;
    }
    const float inv = 1.f / s;
#pragma unroll 4
    for (int d = 0; d < 48; ++d) G[r * 48 + d] = L[d] * inv;
  }
  __syncthreads();
  if (tid < 192) {  // Weff row o = tid
    const int o = tid;
    f32x4 acc[12];
#pragma unroll
    for (int dv = 0; dv < 12; ++dv) acc[dv] = (f32x4){0.f, 0.f, 0.f, 0.f};
    for (int c = 0; c < 48; ++c) {
      const float w = wp[o * 49 + c];
      const f32x4* at = (const f32x4*)(G + c * 48);  // broadcast reads
#pragma unroll
      for (int dv = 0; dv < 12; ++dv) acc[dv] += w * at[dv];
    }
    u16* op = weff + ((size_t)b * 192 + o) * 192 + h * 48;
#pragma unroll
    for (int g8 = 0; g8 < 6; ++g8) {
      u16x8 ov;
#pragma unroll
      for (int j = 0; j < 8; ++j) {
        const int d = g8 * 8 + j;
        ov[j] = f2bf(acc[d >> 2][d & 3]);
      }
      *(u16x8*)(op + g8 * 8) = ov;
    }
  }
}

// ---------------------------------------------------------------------------
extern "C" void kernel_launch(void* const* d_in, const int* in_sizes, int n_in,
                              void* d_out, int out_size, void* d_ws,
                              size_t ws_size, hipStream_t stream) {
  (void)in_sizes; (void)n_in; (void)out_size; (void)ws_size;
  const float* x      = (const float*)d_in[0];  // [4][192][128][128]
  const float* w_qkv  = (const float*)d_in[1];  // [576][192]
  const float* w_dw   = (const float*)d_in[2];  // [576][9]
  const float* w_proj = (const float*)d_in[3];  // [192][192]
  const float* temp   = (const float*)d_in[4];  // [4]

  char* ws = (char*)d_ws;
  u16*   qkv     = (u16*)ws;                    // 75,497,472 B
  float* partial = (float*)(ws + 75497472);     //  4,718,592 B [16][2304][32]
  float* sq      = (float*)(ws + 80216064);     //      9,216 B
  u16*   Wq      = (u16*)(ws + 80225280);       //    221,184 B
  u16*   Weff    = (u16*)(ws + 80446464);       //    294,912 B  (end 80.7 MB)

  // w_qkv -> bf16
  convert_w_kernel<<<dim3(432), 256, 0, stream>>>(w_qkv, Wq, 110592);
  // qkv[b][o][n] = sum_c x[c][n]*Wq[o][c]  (fused x-transpose in staging)
  gemm_bt_kernel<true, true, 9><<<dim3(512), 256, 0, stream>>>(
      x, Wq, qkv, (size_t)192 * 16384, 0, (size_t)576 * 16384, 16384);
  // depthwise 3x3 in-place + per-channel sum-of-squares
  dwconv_kernel<<<dim3(576, 4), 256, 0, stream>>>(qkv, w_dw, sq);
  // gram partials: 32 chunk-groups per (b,h), in-block wave reduction
  gram_kernel<<<dim3(32, 16), 256, 0, stream>>>(qkv, partial);
  // reduce + normalize + softmax + fold into projection
  softmax_weff_kernel<<<dim3(16), 256, 0, stream>>>(partial, sq, temp, w_proj,
                                                    Weff);
  // out[b][o][n] = sum_c2 v[c2][n]*Weff[o][c2] (fused v-transpose in staging)
  gemm_bt_kernel<false, false, 3><<<dim3(512), 256, 0, stream>>>(
      qkv + (size_t)384 * 16384, Weff, d_out, (size_t)576 * 16384,
      (size_t)192 * 192, (size_t)192 * 16384, 16384);
}

// Round 6
// 131.724 us; speedup vs baseline: 1.5815x; 1.0420x over previous
//
#include <hip/hip_runtime.h>

typedef unsigned short u16;
typedef float f32x4 __attribute__((ext_vector_type(4)));
typedef __bf16 bf16x8 __attribute__((ext_vector_type(8)));
typedef unsigned short u16x8 __attribute__((ext_vector_type(8)));
typedef unsigned short u16x4 __attribute__((ext_vector_type(4)));

#define DEV static __device__ __forceinline__

DEV u16 f2bf(float f) {
  unsigned int u = __float_as_uint(f);
  u += 0x7FFFu + ((u >> 16) & 1u);   // round-to-nearest-even
  return (u16)(u >> 16);
}
DEV float bf2f(u16 h) { return __uint_as_float(((unsigned int)h) << 16); }

// async global->LDS, 16B per lane. LDS dest = wave-uniform base + lane*16.
DEV void gload_lds16(const void* g, void* l) {
  __builtin_amdgcn_global_load_lds(
      (__attribute__((address_space(1))) void*)(unsigned long long)g,
      (__attribute__((address_space(3))) void*)l, 16, 0, 0);
}

// ---------------------------------------------------------------------------
// K0b: convert w_qkv fp32 -> bf16
__global__ __launch_bounds__(256) void convert_w_kernel(
    const float* __restrict__ in, u16* __restrict__ out, int n) {
  int i = blockIdx.x * 256 + threadIdx.x;
  if (i < n) out[i] = f2bf(in[i]);
}

// ---------------------------------------------------------------------------
// B^T GEMM with fused A-transpose. C[j][m] = sum_k A^T[m][k]*B[j][k], K=192.
// BM=64 (sA 24 KB + sB 24 KB = 48 KB -> 3 blocks/CU). A source is
// channel-planar [192][16384] (fp32 x, or bf16 v); block owns 64 consecutive
// pixels, stages A-tile [64 n][192 c] bf16 via register transpose+convert at
// XOR-swizzled addresses ((c*2) ^ ((n&7)<<4)) matching the fragment reads.
// j-loop per iter: read B_j frags | lgkm+bar | prefetch B_{j+1} (6 loads) |
// store acc(j-1) (4 stores) | MFMA 24 | vmcnt(4)+bar.
// vmcnt(4) = this iter's 4 stores may stay in flight; loads + older stores
// are forced complete (FIFO). Stores get a full iteration of slack.
template <bool IN_F32, bool OUT_BF16, int NJ>
__global__ __launch_bounds__(256, 3) void gemm_bt_kernel(
    const void* __restrict__ Av, const u16* __restrict__ B,
    void* __restrict__ Cv, size_t aBatch, size_t bBatch, size_t cBatch,
    int ldC) {
  __shared__ __align__(16) char smem[49152];
  char* sA = smem;            // [64][384 B] content-swizzled
  char* sB = smem + 24576;    // [64][384 B] content-swizzled

  const int tid = threadIdx.x, wave = tid >> 6, lane = tid & 63;
  const int id = blockIdx.x;
  const int m0 = (id & 255) * 64, b = id >> 8;

  // ---- A-staging: fused transpose (+convert)
  if (IN_F32) {
    const float* Xb = (const float*)Av + (size_t)b * aBatch + m0;
    const int cbl = tid & 15, iq = tid >> 4;  // 16 c-quads x 16 n-quads
#pragma unroll
    for (int pass = 0; pass < 3; ++pass) {
      const int cb = pass * 16 + cbl;
      f32x4 v[4];
#pragma unroll
      for (int r = 0; r < 4; ++r)
        v[r] = *(const f32x4*)(Xb + (size_t)(cb * 4 + r) * 16384 + iq * 4);
#pragma unroll
      for (int j = 0; j < 4; ++j) {
        const int n = iq * 4 + j;
        u16x4 col;
        col[0] = f2bf(v[0][j]);
        col[1] = f2bf(v[1][j]);
        col[2] = f2bf(v[2][j]);
        col[3] = f2bf(v[3][j]);
        *(u16x4*)(sA + n * 384 + ((cb * 8) ^ ((n & 7) << 4))) = col;
      }
    }
  } else {
    const u16* Vb = (const u16*)Av + (size_t)b * aBatch + m0;
#pragma unroll
    for (int pass = 0; pass < 2; ++pass) {
      const int task = pass * 256 + tid;  // 48 c-quads x 8 n-octs = 384 tasks
      if (task < 384) {
        const int cb = task >> 3, io = task & 7;
        u16x8 v[4];
#pragma unroll
        for (int r = 0; r < 4; ++r)
          v[r] = *(const u16x8*)(Vb + (size_t)(cb * 4 + r) * 16384 + io * 8);
#pragma unroll
        for (int j = 0; j < 8; ++j) {
          const int n = io * 8 + j;
          u16x4 col;
          col[0] = v[0][j];
          col[1] = v[1][j];
          col[2] = v[2][j];
          col[3] = v[3][j];
          *(u16x4*)(sA + n * 384 + ((cb * 8) ^ ((n & 7) << 4))) = col;
        }
      }
    }
  }
  // ---- stage B_0 (24 KB, 6 chunks/wave)
  const char* Bbase = (const char*)(B + (size_t)b * bBatch);
#pragma unroll
  for (int i = 0; i < 6; ++i) {
    const int c = i * 4 + wave;
    const int d = c * 1024 + lane * 16;
    const int row = d / 384, inrow = d - row * 384;
    gload_lds16(Bbase + row * 384 + (inrow ^ ((row & 7) << 4)), sB + c * 1024);
  }
  asm volatile("s_waitcnt vmcnt(0) lgkmcnt(0)" ::: "memory");
  __builtin_amdgcn_s_barrier();

  const int wm = wave & 1, wn = wave >> 1;
  const int l15 = lane & 15, lg = lane >> 4;
  const int swm = (l15 & 7) << 4;
  const int rA0 = (wm * 32 + l15) * 384;
  const int rB0 = (wn * 32 + l15) * 384;

  // ---- A fragments to registers, reused for all j
  bf16x8 af[2][6];
#pragma unroll
  for (int mi = 0; mi < 2; ++mi)
#pragma unroll
    for (int ks = 0; ks < 6; ++ks)
      af[mi][ks] = *(const bf16x8*)(sA + rA0 + mi * 16 * 384 +
                                    ((ks * 64 + lg * 16) ^ swm));

  f32x4 acc[2][2];
#pragma unroll 1
  for (int j = 0; j < NJ; ++j) {
    // read B_j fragments
    bf16x8 bfv[2][6];
#pragma unroll
    for (int nj = 0; nj < 2; ++nj)
#pragma unroll
      for (int ks = 0; ks < 6; ++ks)
        bfv[nj][ks] = *(const bf16x8*)(sB + rB0 + nj * 16 * 384 +
                                       ((ks * 64 + lg * 16) ^ swm));
    asm volatile("s_waitcnt lgkmcnt(0)" ::: "memory");
    __builtin_amdgcn_s_barrier();  // all waves consumed sB -> overwritable
    // prefetch B_{j+1} FIRST (so vmcnt(4) below covers them, not stores)
    if (j + 1 < NJ) {
      const char* Bj = Bbase + (size_t)(j + 1) * 24576;
#pragma unroll
      for (int i = 0; i < 6; ++i) {
        const int c = i * 4 + wave;
        const int d = c * 1024 + lane * 16;
        const int row = d / 384, inrow = d - row * 384;
        gload_lds16(Bj + row * 384 + (inrow ^ ((row & 7) << 4)), sB + c * 1024);
      }
    }
    // store previous tile (stores stay in flight through next iter)
    if (j > 0) {
      const int j0 = (j - 1) * 64;
      if (OUT_BF16) {
        u16* Cb = (u16*)Cv + (size_t)b * cBatch;
#pragma unroll
        for (int mi = 0; mi < 2; ++mi)
#pragma unroll
          for (int nj = 0; nj < 2; ++nj) {
            u16x4 ov;
#pragma unroll
            for (int r = 0; r < 4; ++r) ov[r] = f2bf(acc[mi][nj][r]);
            *(u16x4*)(Cb + (size_t)(j0 + wn * 32 + nj * 16 + l15) * ldC + m0 +
                      wm * 32 + mi * 16 + lg * 4) = ov;
          }
      } else {
        float* Cb = (float*)Cv + (size_t)b * cBatch;
#pragma unroll
        for (int mi = 0; mi < 2; ++mi)
#pragma unroll
          for (int nj = 0; nj < 2; ++nj)
            *(f32x4*)(Cb + (size_t)(j0 + wn * 32 + nj * 16 + l15) * ldC + m0 +
                      wm * 32 + mi * 16 + lg * 4) = acc[mi][nj];
      }
    }
    __builtin_amdgcn_sched_barrier(0);  // pin: loads+stores issued before MFMA
#pragma unroll
    for (int mi = 0; mi < 2; ++mi)
#pragma unroll
      for (int nj = 0; nj < 2; ++nj) acc[mi][nj] = (f32x4){0.f, 0.f, 0.f, 0.f};
#pragma unroll
    for (int ks = 0; ks < 6; ++ks)
#pragma unroll
      for (int mi = 0; mi < 2; ++mi)
#pragma unroll
        for (int nj = 0; nj < 2; ++nj)
          acc[mi][nj] = __builtin_amdgcn_mfma_f32_16x16x32_bf16(
              af[mi][ks], bfv[nj][ks], acc[mi][nj], 0, 0, 0);
    if (j + 1 < NJ) {
      if (j == 0)
        asm volatile("s_waitcnt vmcnt(0)" ::: "memory");
      else
        asm volatile("s_waitcnt vmcnt(4)" ::: "memory");
      __builtin_amdgcn_s_barrier();
    }
  }
  // final tile store
  {
    const int j0 = (NJ - 1) * 64;
    if (OUT_BF16) {
      u16* Cb = (u16*)Cv + (size_t)b * cBatch;
#pragma unroll
      for (int mi = 0; mi < 2; ++mi)
#pragma unroll
        for (int nj = 0; nj < 2; ++nj) {
          u16x4 ov;
#pragma unroll
          for (int r = 0; r < 4; ++r) ov[r] = f2bf(acc[mi][nj][r]);
          *(u16x4*)(Cb + (size_t)(j0 + wn * 32 + nj * 16 + l15) * ldC + m0 +
                    wm * 32 + mi * 16 + lg * 4) = ov;
        }
    } else {
      float* Cb = (float*)Cv + (size_t)b * cBatch;
#pragma unroll
      for (int mi = 0; mi < 2; ++mi)
#pragma unroll
        for (int nj = 0; nj < 2; ++nj)
          *(f32x4*)(Cb + (size_t)(j0 + wn * 32 + nj * 16 + l15) * ldC + m0 +
                    wm * 32 + mi * 16 + lg * 4) = acc[mi][nj];
    }
  }
}

// ---------------------------------------------------------------------------
// Depthwise 3x3 (pad 1), in-place on bf16 [b][576][128][128]; per-channel
// sum-of-squares for the q/k L2 norms. One block per (b, channel).
__global__ __launch_bounds__(256) void dwconv_kernel(
    u16* __restrict__ qkv, const float* __restrict__ wdw,
    float* __restrict__ sq) {
  __shared__ u16 img[16384];  // full 128x128 channel, 32 KB
  __shared__ float red[4];
  const int o = blockIdx.x, b = blockIdx.y;
  const size_t base = ((size_t)b * 576 + o) * 16384;
  const int tid = threadIdx.x, wave = tid >> 6, lane = tid & 63;
#pragma unroll
  for (int i = 0; i < 8; ++i) {
    const int off = (i * 4 + wave) * 1024;
    gload_lds16((const char*)qkv + base * 2 + off + lane * 16, (char*)img + off);
  }
  asm volatile("s_waitcnt vmcnt(0)" ::: "memory");
  __syncthreads();
  float w[9];
#pragma unroll
  for (int j = 0; j < 9; ++j) w[j] = wdw[o * 9 + j];
  float sqacc = 0.f;
  for (int it = 0; it < 8; ++it) {
    const int chunk = it * 256 + tid;  // 2048 chunks of 8 px
    const int px0 = chunk * 8;
    const int y = px0 >> 7, x0 = px0 & 127;
    float acc[8];
#pragma unroll
    for (int j = 0; j < 8; ++j) acc[j] = 0.f;
#pragma unroll
    for (int dy = -1; dy <= 1; ++dy) {
      const int yy = y + dy;
      float v[10];
      if (yy >= 0 && yy <= 127) {
        const u16* rowp = img + yy * 128 + x0;
        u16x8 m = *(const u16x8*)rowp;
#pragma unroll
        for (int j = 0; j < 8; ++j) v[j + 1] = bf2f(m[j]);
        v[0] = (x0 > 0) ? bf2f(rowp[-1]) : 0.f;
        v[9] = (x0 < 120) ? bf2f(rowp[8]) : 0.f;
      } else {
#pragma unroll
        for (int j = 0; j < 10; ++j) v[j] = 0.f;
      }
      const float w0 = w[(dy + 1) * 3], w1 = w[(dy + 1) * 3 + 1],
                  w2 = w[(dy + 1) * 3 + 2];
#pragma unroll
      for (int j = 0; j < 8; ++j) acc[j] += w0 * v[j] + w1 * v[j + 1] + w2 * v[j + 2];
    }
    u16x8 ov;
#pragma unroll
    for (int j = 0; j < 8; ++j) {
      sqacc += acc[j] * acc[j];
      ov[j] = f2bf(acc[j]);
    }
    *(u16x8*)(qkv + base + px0) = ov;  // in-place: all reads came from LDS
  }
#pragma unroll
  for (int s = 32; s > 0; s >>= 1) sqacc += __shfl_xor(sqacc, s, 64);
  if (lane == 0) red[wave] = sqacc;
  __syncthreads();
  if (tid == 0) sq[b * 576 + o] = red[0] + red[1] + red[2] + red[3];
}

// ---------------------------------------------------------------------------
// Gram: G_partial[c][d] = sum_n q[c][n]*k[d][n] over a 512-n block (4 waves x
// 128 n each, reduced in-block through LDS). Tile content XOR-swizzled.
// grid (32 chunk-groups, 16 bh); partial[bh][pos][chunk32].
__global__ __launch_bounds__(256) void gram_kernel(
    const u16* __restrict__ qkv, float* __restrict__ partial) {
  __shared__ u16 tiles[4 * 3072];   // per-wave [96][32] bf16 (q 0-47, k 48-95)
  __shared__ float red[4 * 2304];   // per-wave gram copies for in-block reduce
  const int bh = blockIdx.y, b = bh >> 2, h = bh & 3;
  const int g = blockIdx.x;                  // chunk 0..31
  const int wave = threadIdx.x >> 6, lane = threadIdx.x & 63;
  const int n0 = g * 512 + wave * 128;
  const u16* qb = qkv + ((size_t)b * 576 + h * 48) * 16384;
  const u16* kb = qb + (size_t)192 * 16384;
  char* tl = (char*)(tiles + wave * 3072);
  const int l15 = lane & 15, lg = lane >> 4;
  const int swz = (l15 & 3) << 4;
  f32x4 acc[3][3];
#pragma unroll
  for (int i = 0; i < 3; ++i)
#pragma unroll
    for (int j = 0; j < 3; ++j) acc[i][j] = (f32x4){0.f, 0.f, 0.f, 0.f};

  for (int ks = 0; ks < 4; ++ks) {
    const int nn = n0 + ks * 32;
    asm volatile("s_waitcnt lgkmcnt(0)" ::: "memory");
#pragma unroll
    for (int i = 0; i < 6; ++i) {
      const int flat = i * 1024 + lane * 16;
      const int row = flat >> 6, colb = flat & 63;
      const u16* src = (row < 48) ? (qb + (size_t)row * 16384 + nn)
                                  : (kb + (size_t)(row - 48) * 16384 + nn);
      gload_lds16((const char*)src + (colb ^ ((row & 3) << 4)), tl + i * 1024);
    }
    asm volatile("s_waitcnt vmcnt(0)" ::: "memory");
    bf16x8 qf[3], kf[3];
#pragma unroll
    for (int f = 0; f < 3; ++f) {
      qf[f] = *(const bf16x8*)(tl + (f * 16 + l15) * 64 + ((lg * 16) ^ swz));
      kf[f] = *(const bf16x8*)(tl + (48 + f * 16 + l15) * 64 + ((lg * 16) ^ swz));
    }
#pragma unroll
    for (int i = 0; i < 3; ++i)
#pragma unroll
      for (int j = 0; j < 3; ++j)
        acc[i][j] = __builtin_amdgcn_mfma_f32_16x16x32_bf16(qf[i], kf[j],
                                                            acc[i][j], 0, 0, 0);
  }
  // in-block reduce over the 4 waves
  {
    float* rw = red + wave * 2304;
#pragma unroll
    for (int i = 0; i < 3; ++i)
#pragma unroll
      for (int j = 0; j < 3; ++j)
#pragma unroll
        for (int r = 0; r < 4; ++r)
          rw[(i * 16 + lg * 4 + r) * 48 + (j * 16 + l15)] = acc[i][j][r];
  }
  __syncthreads();
#pragma unroll
  for (int it = 0; it < 9; ++it) {
    const int p = it * 256 + threadIdx.x;
    const float s = red[p] + red[2304 + p] + red[4608 + p] + red[6912 + p];
    partial[((size_t)bh * 2304 + p) * 32 + g] = s;
  }
}

// ---------------------------------------------------------------------------
// Wide reduction of gram partials: G[bh*2304+p] = sum over 32 chunks.
// 128 B contiguous per thread, 144 blocks -> full-BW, no latency chain.
__global__ __launch_bounds__(256) void reduce_partial_kernel(
    const float* __restrict__ partial, float* __restrict__ G) {
  const int idx = blockIdx.x * 256 + threadIdx.x;  // 0..36863
  const f32x4* pp = (const f32x4*)(partial + (size_t)idx * 32);
  const f32x4 a = (pp[0] + pp[1]) + (pp[2] + pp[3]) +
                  (pp[4] + pp[5]) + (pp[6] + pp[7]);
  G[idx] = a.x + a.y + a.z + a.w;
}

// ---------------------------------------------------------------------------
// Normalize, softmax, fold attn into projection (reads pre-reduced G).
__global__ __launch_bounds__(256) void softmax_weff_kernel(
    const float* __restrict__ Gin, const float* __restrict__ sq,
    const float* __restrict__ temp, const float* __restrict__ wproj,
    u16* __restrict__ weff) {
  __shared__ float G[2304];        // gram -> attn (in place)
  __shared__ float wp[192 * 49];   // wproj slice, pad 49 (odd bank stride)
  __shared__ float nq[48], nk[48];
  const int bh = blockIdx.x, b = bh >> 2, h = bh & 3;
  const int tid = threadIdx.x;
#pragma unroll
  for (int it = 0; it < 36; ++it) {  // load wproj [192][h*48 .. h*48+48)
    const int j = it * 256 + tid;
    const int o = j / 48, c = j - o * 48;
    wp[o * 49 + c] = wproj[o * 192 + h * 48 + c];
  }
#pragma unroll
  for (int it = 0; it < 9; ++it) {
    const int p = it * 256 + tid;
    G[p] = Gin[(size_t)bh * 2304 + p];
  }
  if (tid < 48) {
    nq[tid] = fmaxf(sqrtf(sq[b * 576 + h * 48 + tid]), 1e-12f);
    nk[tid] = fmaxf(sqrtf(sq[b * 576 + 192 + h * 48 + tid]), 1e-12f);
  }
  __syncthreads();
  if (tid < 48) {  // row softmax (48 rows)
    const int r = tid;
    const float inq = temp[h] / nq[r];
    float L[48];
    float mx = -3.4e38f;
#pragma unroll 4
    for (int d = 0; d < 48; ++d) {
      const float v = G[r * 48 + d] * inq / nk[d];
      L[d] = v;
      mx = fmaxf(mx, v);
    }
    float s = 0.f;
#pragma unroll 4
    for (int d = 0; d < 48; ++d) {
      const float e = __expf(L[d] - mx);
      L[d] = e;
      s += e;
    }
    const float inv = 1.f / s;
#pragma unroll 4
    for (int d = 0; d < 48; ++d) G[r * 48 + d] = L[d] * inv;
  }
  __syncthreads();
  if (tid < 192) {  // Weff row o = tid
    const int o = tid;
    f32x4 acc[12];
#pragma unroll
    for (int dv = 0; dv < 12; ++dv) acc[dv] = (f32x4){0.f, 0.f, 0.f, 0.f};
    for (int c = 0; c < 48; ++c) {
      const float w = wp[o * 49 + c];
      const f32x4* at = (const f32x4*)(G + c * 48);  // broadcast reads
#pragma unroll
      for (int dv = 0; dv < 12; ++dv) acc[dv] += w * at[dv];
    }
    u16* op = weff + ((size_t)b * 192 + o) * 192 + h * 48;
#pragma unroll
    for (int g8 = 0; g8 < 6; ++g8) {
      u16x8 ov;
#pragma unroll
      for (int j = 0; j < 8; ++j) {
        const int d = g8 * 8 + j;
        ov[j] = f2bf(acc[d >> 2][d & 3]);
      }
      *(u16x8*)(op + g8 * 8) = ov;
    }
  }
}

// ---------------------------------------------------------------------------
extern "C" void kernel_launch(void* const* d_in, const int* in_sizes, int n_in,
                              void* d_out, int out_size, void* d_ws,
                              size_t ws_size, hipStream_t stream) {
  (void)in_sizes; (void)n_in; (void)out_size; (void)ws_size;
  const float* x      = (const float*)d_in[0];  // [4][192][128][128]
  const float* w_qkv  = (const float*)d_in[1];  // [576][192]
  const float* w_dw   = (const float*)d_in[2];  // [576][9]
  const float* w_proj = (const float*)d_in[3];  // [192][192]
  const float* temp   = (const float*)d_in[4];  // [4]

  char* ws = (char*)d_ws;
  u16*   qkv     = (u16*)ws;                    // 75,497,472 B
  float* partial = (float*)(ws + 75497472);     //  4,718,592 B [16][2304][32]
  float* G       = (float*)(ws + 80216064);     //    147,456 B
  float* sq      = (float*)(ws + 80363520);     //      9,216 B
  u16*   Wq      = (u16*)(ws + 80372736);       //    221,184 B
  u16*   Weff    = (u16*)(ws + 80593920);       //    294,912 B  (end 80.9 MB)

  // w_qkv -> bf16
  convert_w_kernel<<<dim3(432), 256, 0, stream>>>(w_qkv, Wq, 110592);
  // qkv[b][o][n] = sum_c x[c][n]*Wq[o][c]  (fused x-transpose in staging)
  gemm_bt_kernel<true, true, 9><<<dim3(1024), 256, 0, stream>>>(
      x, Wq, qkv, (size_t)192 * 16384, 0, (size_t)576 * 16384, 16384);
  // depthwise 3x3 in-place + per-channel sum-of-squares
  dwconv_kernel<<<dim3(576, 4), 256, 0, stream>>>(qkv, w_dw, sq);
  // gram partials: 32 chunk-groups per (b,h), in-block wave reduction
  gram_kernel<<<dim3(32, 16), 256, 0, stream>>>(qkv, partial);
  // wide cross-chunk reduction
  reduce_partial_kernel<<<dim3(144), 256, 0, stream>>>(partial, G);
  // normalize + softmax + fold into projection
  softmax_weff_kernel<<<dim3(16), 256, 0, stream>>>(G, sq, temp, w_proj, Weff);
  // out[b][o][n] = sum_c2 v[c2][n]*Weff[o][c2] (fused v-transpose in staging)
  gemm_bt_kernel<false, false, 3><<<dim3(1024), 256, 0, stream>>>(
      qkv + (size_t)384 * 16384, Weff, d_out, (size_t)576 * 16384,
      (size_t)192 * 192, (size_t)192 * 16384, 16384);
}